// Round 13
// baseline (1489.007 us; speedup 1.0000x reference)
//
#include <hip/hip_runtime.h>

// ---------------- problem constants (match setup_inputs) ----------------
constexpr int Bn = 2, Cn = 3, Hh = 512, Ww = 512;
constexpr int KS = 15, KR = 7;          // PSF kernel
constexpr int NDK = 6, NRK = 5;         // data / reg bank sizes (5x5, r=2)
constexpr int GH = 64, GW = 64, NBn = 9, SS = 8;  // bilateral grid
constexpr float EPSf = 1e-8f;
constexpr float CGTOL = 1e-4f;
constexpr int PLANE = Hh * Ww;
constexpr int CHW = Cn * PLANE;
constexpr int BX = 64, BY = 16;         // gradL tile (4 px/thread)
constexpr int GXc = Ww / BX, GYc = Hh / BY;   // 8 x 32
constexpr int PB = GXc * GYc * Cn;      // 768 partial-blocks per batch (slot2)
constexpr int BY2 = 32;                 // conv15/hess tile height (8 px/thread)
constexpr int GYc2 = Hh / BY2;          // 16
constexpr int PB2 = GXc * GYc2 * Cn;    // 384 partial-blocks (slots 0,1)
constexpr int SA = 80, THt = 30;        // gradL 15x15 halo tile: 78x30, stride 80
constexpr int TH2 = 46;                 // conv15/hess halo rows: 32+14
constexpr int S2W = 72, S2H = 24;       // gradL 5x5 src tile (halo 4): 72x24
constexpr int S2H2 = 40;                // hess 5x5 src rows: 32+8
constexpr int PHW = 68, PHH = 20;       // gradL mid tile (halo 2): 68x20
constexpr int PHH2 = 36;                // hess mid rows: 32+4
constexpr int PHG = (PHW / 4) * PHH;    // 340 float4-groups (gradL)
constexpr int PHG2 = (PHW / 4) * PHH2;  // 612 float4-groups (hess)
constexpr int NITER = 5;

struct CgState { float alpha, beta, rn, r0; int done, pflag; int pad0, pad1; };

struct SolveInfo {
    int fastBank; int allrp2; int nd; int pad;
    float sctot;
    float dsc[NDK]; int ddy[NDK], ddx[NDK];
    float C[81];       // composite reg stencil (coef-weighted autocorrelation)
};

__device__ __forceinline__ float blockReduce(float v, float* red, int tid) {
    red[tid] = v; __syncthreads();
    for (int s = 128; s > 0; s >>= 1) { if (tid < s) red[tid] += red[tid + s]; __syncthreads(); }
    float r = red[0]; __syncthreads();
    return r;
}

// ---------------------------------------------------------------------
// k_comp: build SolveInfo for each solve index (2 blocks).
// ---------------------------------------------------------------------
__global__ __launch_bounds__(128)
void k_comp(const float* __restrict__ dkw, const float* __restrict__ dks,
            const float* __restrict__ rkw, const float* __restrict__ rpw,
            const float* __restrict__ rks, SolveInfo* si)
{
    const int idx = blockIdx.x;
    SolveInfo* s = si + idx;
    const float* dkw_i = dkw + idx * NDK;
    const float* dks_i = dks + (size_t)idx * NDK * 25;
    const float* rkw_i = rkw + idx * NRK;
    const float* rpw_i = rpw + idx * NRK;
    const float* rks_i = rks + (size_t)idx * NRK * 25;
    const int t = threadIdx.x;
    if (t < 81) {
        int oy = t / 9 - 4, ox = t % 9 - 4;
        float acc = 0.f;
        for (int m = 0; m < NRK; m++) {
            float wm = rkw_i[m], rp = rpw_i[m];
            float ch = wm * rp * (rp - 1.f);
            if (ch == 0.f) continue;
            for (int ay = 0; ay < 5; ay++)
                for (int ax = 0; ax < 5; ax++) {
                    int by = ay - oy, bx = ax - ox;
                    if (by < 0 || by >= 5 || bx < 0 || bx >= 5) continue;
                    acc += ch * rks_i[m * 25 + ay * 5 + ax] * rks_i[m * 25 + by * 5 + bx];
                }
        }
        s->C[t] = acc;
    }
    if (t == 81) {
        int fast = 1, nd = 0; float tot = 0.f;
        for (int n = 0; n < NDK; n++) {
            if (dkw_i[n] == 0.f) continue;
            int cntz = 0, pos = -1;
            for (int q = 0; q < 25; q++) if (dks_i[n * 25 + q] != 0.f) { cntz++; pos = q; }
            if (cntz > 1) fast = 0;
            if (cntz == 1 && nd < NDK) {
                float v = dks_i[n * 25 + pos];
                s->dsc[nd] = 2.f * dkw_i[n] * v * v;
                s->ddy[nd] = pos / 5 - 2; s->ddx[nd] = pos % 5 - 2;
                tot += s->dsc[nd]; nd++;
            }
        }
        s->fastBank = fast; s->nd = fast ? nd : 0; s->sctot = tot;
    }
    if (t == 82) {
        int ok = 1;
        for (int m = 0; m < NRK; m++) {
            float wm = rkw_i[m], rp = rpw_i[m];
            if (wm != 0.f && rp != 2.f && wm * rp * (rp - 1.f) != 0.f) ok = 0;
        }
        s->allrp2 = ok;
    }
}

// ---------------------------------------------------------------------
// k_conv15: 15x15 correlation, 64x32 tile, 8 px/thread (2 rows x 4 cols).
// Dual-row reuse: each loaded 20-float window serves both output rows.
// mode 0: v=src, copy v->aux2; out=corr(v)-sub   mode 3: no copy
// mode 2: v=p_cur=pflag?r+beta*p:p; persist->aux2; out=corr(v); num->slot0
// fastBank composite folded into output.
// ---------------------------------------------------------------------
__global__ __launch_bounds__(256)
void k_conv15(const float* __restrict__ src, const float* __restrict__ rb,
              const float* __restrict__ pbuf, float* __restrict__ aux2,
              const float* __restrict__ sub, float* __restrict__ out,
              const float* __restrict__ kernB, float* __restrict__ part,
              const SolveInfo* __restrict__ si,
              const CgState* __restrict__ st, const int* __restrict__ ncg,
              int iter, int mode)
{
    const int pz = blockIdx.z, b = pz / Cn, c = pz % Cn;
    const CgState s = st[b];
    if (mode == 2 && (s.done != 0 || iter >= *ncg)) return;
    __shared__ __align__(16) float tile[SA * TH2];
    __shared__ float red[256];
    const int tx = threadIdx.x, ty = threadIdx.y, tid = ty * 16 + tx;
    const int ox0 = blockIdx.x * BX, oy0 = blockIdx.y * BY2;
    const int baseP = pz * PLANE;
    const float beta = s.beta; const int pf = s.pflag;
    const float* kp = kernB + b * 225;

    float nm = 0.f;
    for (int i = tid; i < 78 * TH2; i += 256) {
        int ly = i / 78, lx = i % 78;
        int gy = oy0 - KR + ly, gx = ox0 - KR + lx;
        float v = 0.f;
        if (gy >= 0 && gy < Hh && gx >= 0 && gx < Ww) {
            int gi = baseP + gy * Ww + gx;
            if (mode == 2) {
                float rv = rb[gi], pv = pbuf[gi];
                v = pf ? fmaf(beta, pv, rv) : pv;
                if (ly >= KR && ly < KR + BY2 && lx >= KR && lx < KR + BX) {
                    nm = fmaf(rv, v, nm);
                    aux2[gi] = v;            // persist p_cur (own tile only)
                }
            } else {
                v = src[gi];
                if (mode == 0 && ly >= KR && ly < KR + BY2 && lx >= KR && lx < KR + BX)
                    aux2[gi] = v;
            }
        }
        tile[ly * SA + lx] = v;
    }
    __syncthreads();

    const int colbase = tx * 4;
    const int ry = ty * 2;
    float aA0 = 0.f, aA1 = 0.f, aA2 = 0.f, aA3 = 0.f;
    float aB0 = 0.f, aB1 = 0.f, aB2 = 0.f, aB3 = 0.f;
    for (int i = 0; i < 16; i++) {
        const float4* rp4 = reinterpret_cast<const float4*>(&tile[(ry + i) * SA + colbase]);
        float f[20];
        #pragma unroll
        for (int s5 = 0; s5 < 5; s5++) {
            float4 w4 = rp4[s5];
            f[s5 * 4] = w4.x; f[s5 * 4 + 1] = w4.y; f[s5 * 4 + 2] = w4.z; f[s5 * 4 + 3] = w4.w;
        }
        if (i < 15) {
            const float* krA = kp + i * 15;
            #pragma unroll
            for (int j = 0; j < KS; j++) {
                float kv = krA[j];
                aA0 = fmaf(kv, f[j], aA0); aA1 = fmaf(kv, f[j + 1], aA1);
                aA2 = fmaf(kv, f[j + 2], aA2); aA3 = fmaf(kv, f[j + 3], aA3);
            }
        }
        if (i >= 1) {
            const float* krB = kp + (i - 1) * 15;
            #pragma unroll
            for (int j = 0; j < KS; j++) {
                float kv = krB[j];
                aB0 = fmaf(kv, f[j], aB0); aB1 = fmaf(kv, f[j + 1], aB1);
                aB2 = fmaf(kv, f[j + 2], aB2); aB3 = fmaf(kv, f[j + 3], aB3);
            }
        }
    }
    const int gyA = oy0 + ry, gx0 = ox0 + colbase;
    #pragma unroll
    for (int rr = 0; rr < 2; rr++) {
        const int gy = gyA + rr;
        float a0 = rr ? aB0 : aA0, a1 = rr ? aB1 : aA1;
        float a2 = rr ? aB2 : aA2, a3 = rr ? aB3 : aA3;
        const int gi = baseP + gy * Ww + gx0;
        if (sub) {
            float4 sv = *reinterpret_cast<const float4*>(&sub[gi]);
            a0 -= sv.x; a1 -= sv.y; a2 -= sv.z; a3 -= sv.w;
        }
        if (si->fastBank) {
            if (gy >= 2 && gy <= Hh - 3 && gx0 >= 2 && gx0 + 3 <= Ww - 3) {
                float sc = si->sctot;
                a0 *= sc; a1 *= sc; a2 *= sc; a3 *= sc;
            } else {
                float m0 = 0.f, m1 = 0.f, m2 = 0.f, m3 = 0.f;
                int ndl = si->nd;
                for (int n = 0; n < ndl; n++) {
                    float sc = si->dsc[n]; int dy = si->ddy[n], dx = si->ddx[n];
                    if (gy - dy < 0 || gy - dy >= Hh) continue;
                    if (gx0     - dx >= 0 && gx0     - dx < Ww) m0 += sc;
                    if (gx0 + 1 - dx >= 0 && gx0 + 1 - dx < Ww) m1 += sc;
                    if (gx0 + 2 - dx >= 0 && gx0 + 2 - dx < Ww) m2 += sc;
                    if (gx0 + 3 - dx >= 0 && gx0 + 3 - dx < Ww) m3 += sc;
                }
                a0 *= m0; a1 *= m1; a2 *= m2; a3 *= m3;
            }
        }
        *reinterpret_cast<float4*>(&out[gi]) = make_float4(a0, a1, a2, a3);
    }
    if (mode == 2) {
        float tot = blockReduce(nm, red, tid);
        if (tid == 0) {
            int blk = c * (GXc * GYc2) + blockIdx.y * GXc + blockIdx.x;
            part[((size_t)b * 4 + 0) * PB + blk] = tot;
        }
    }
}

// ---------------------------------------------------------------------
// k_bank: generic data-bank composite (only when !fastBank). 64x16 tile.
// ---------------------------------------------------------------------
__global__ __launch_bounds__(256)
void k_bank(const float* __restrict__ sbuf, float* __restrict__ tbuf,
            const float* __restrict__ dks, const float* __restrict__ dkw,
            const SolveInfo* __restrict__ si,
            const CgState* __restrict__ st, const int* __restrict__ ncg,
            int iter, int mode)
{
    if (si->fastBank) return;
    const int pz = blockIdx.z, b = pz / Cn;
    if (mode == 1 && (st[b].done != 0 || iter >= *ncg)) return;
    __shared__ __align__(16) float sl[S2W * S2H];
    __shared__ __align__(16) float dl[PHW * PHH];
    __shared__ float dkk[NDK * 25];
    __shared__ float dww[NDK];
    const int tx = threadIdx.x, ty = threadIdx.y, tid = ty * 16 + tx;
    const int ox0 = blockIdx.x * BX, oy0 = blockIdx.y * BY;
    const int baseP = pz * PLANE;
    const int colbase = tx * 4;
    for (int i = tid; i < NDK * 25; i += 256) dkk[i] = dks[i];
    if (tid < NDK) dww[tid] = dkw[tid];
    for (int i = tid; i < S2W * S2H; i += 256) {
        int ly = i / S2W, lx = i % S2W;
        int gy = oy0 - 4 + ly, gx = ox0 - 4 + lx;
        sl[i] = (gy >= 0 && gy < Hh && gx >= 0 && gx < Ww) ? sbuf[baseP + gy * Ww + gx] : 0.f;
    }
    __syncthreads();
    float t0 = 0.f, t1 = 0.f, t2 = 0.f, t3 = 0.f;
    for (int n = 0; n < NDK; n++) {
        float wn = 2.f * dww[n];
        if (wn == 0.f) continue;
        float dnr[25];
        #pragma unroll
        for (int q = 0; q < 25; q++) dnr[q] = dkk[n * 25 + q];
        for (int t = tid; t < PHG; t += 256) {
            int zy = t / 17, zx0 = (t % 17) * 4;
            int gy = oy0 - 2 + zy, gx0 = ox0 - 2 + zx0;
            float v0 = 0.f, v1 = 0.f, v2 = 0.f, v3 = 0.f;
            #pragma unroll
            for (int a = 0; a < 5; a++) {
                bool rz = dnr[a*5]==0.f && dnr[a*5+1]==0.f && dnr[a*5+2]==0.f &&
                          dnr[a*5+3]==0.f && dnr[a*5+4]==0.f;
                if (rz) continue;
                const float4* s4 = reinterpret_cast<const float4*>(&sl[(zy + a) * S2W + zx0]);
                float4 u0 = s4[0], u1 = s4[1];
                float f8[8] = {u0.x,u0.y,u0.z,u0.w,u1.x,u1.y,u1.z,u1.w};
                #pragma unroll
                for (int bb = 0; bb < 5; bb++) {
                    float kv = dnr[a * 5 + bb];
                    if (kv != 0.f) {
                        v0 = fmaf(kv, f8[bb], v0); v1 = fmaf(kv, f8[bb+1], v1);
                        v2 = fmaf(kv, f8[bb+2], v2); v3 = fmaf(kv, f8[bb+3], v3);
                    }
                }
            }
            bool gyin = (gy >= 0 && gy < Hh);
            if (!gyin || gx0     < 0 || gx0     >= Ww) v0 = 0.f;
            if (!gyin || gx0 + 1 < 0 || gx0 + 1 >= Ww) v1 = 0.f;
            if (!gyin || gx0 + 2 < 0 || gx0 + 2 >= Ww) v2 = 0.f;
            if (!gyin || gx0 + 3 < 0 || gx0 + 3 >= Ww) v3 = 0.f;
            *reinterpret_cast<float4*>(&dl[zy * PHW + zx0]) = make_float4(v0, v1, v2, v3);
        }
        __syncthreads();
        float c0 = 0.f, c1 = 0.f, c2 = 0.f, c3 = 0.f;
        #pragma unroll
        for (int a = 0; a < 5; a++) {
            int fr = 4 - a;
            bool rz = dnr[fr*5]==0.f && dnr[fr*5+1]==0.f && dnr[fr*5+2]==0.f &&
                      dnr[fr*5+3]==0.f && dnr[fr*5+4]==0.f;
            if (rz) continue;
            const float4* q4 = reinterpret_cast<const float4*>(&dl[(ty + a) * PHW + colbase]);
            float4 u0 = q4[0], u1 = q4[1];
            float f8[8] = {u0.x,u0.y,u0.z,u0.w,u1.x,u1.y,u1.z,u1.w};
            #pragma unroll
            for (int bb = 0; bb < 5; bb++) {
                float kv = dnr[fr * 5 + (4 - bb)];
                if (kv != 0.f) {
                    c0 = fmaf(kv, f8[bb], c0); c1 = fmaf(kv, f8[bb+1], c1);
                    c2 = fmaf(kv, f8[bb+2], c2); c3 = fmaf(kv, f8[bb+3], c3);
                }
            }
        }
        t0 = fmaf(wn, c0, t0); t1 = fmaf(wn, c1, t1);
        t2 = fmaf(wn, c2, t2); t3 = fmaf(wn, c3, t3);
        __syncthreads();
    }
    const int gi = baseP + (oy0 + ty) * Ww + ox0 + colbase;
    *reinterpret_cast<float4*>(&tbuf[gi]) = make_float4(t0, t1, t2, t3);
}

// ---------------------------------------------------------------------
// k_hess (hot path, allrp2): q = corr15T(w) + reg Hessian; 64x32 tile,
// 8 px/thread dual-row reuse. Interior: 9x9 C stencil. Border blocks:
// block-uniform two-pass LDS path (ph aliased into dead wt). slot1 = p.q.
// ---------------------------------------------------------------------
__global__ __launch_bounds__(256)
void k_hess(const float* __restrict__ kx, const float* __restrict__ wb,
            const float* __restrict__ pn,
            float* __restrict__ qb, const float* __restrict__ kernB,
            const float* __restrict__ rks, const float* __restrict__ rkw,
            const float* __restrict__ rpw, const SolveInfo* __restrict__ si,
            float* __restrict__ part, const CgState* __restrict__ st,
            const int* __restrict__ ncg, int iter)
{
    if (!si->allrp2) return;
    const int pz = blockIdx.z, b = pz / Cn, c = pz % Cn;
    const CgState s = st[b];
    if (s.done != 0 || iter >= *ncg) return;
    __shared__ __align__(16) float wt[SA * TH2];     // also reused as ph
    __shared__ __align__(16) float s2[S2W * S2H2];
    __shared__ __align__(16) float sC[81];
    __shared__ float rk5[NRK * 25];
    __shared__ float srkw[NRK], srpw[NRK];
    __shared__ float red[256];
    float* ph = wt;                                  // alias: wt dead after corr15T
    const int tx = threadIdx.x, ty = threadIdx.y, tid = ty * 16 + tx;
    const int ox0 = blockIdx.x * BX, oy0 = blockIdx.y * BY2;
    const int baseP = pz * PLANE;
    const float* wsrc = si->fastBank ? kx : wb;
    const float* kp = kernB + b * 225;

    for (int i = tid; i < 81; i += 256) sC[i] = si->C[i];
    for (int i = tid; i < NRK * 25; i += 256) rk5[i] = rks[i];
    if (tid < NRK) { srkw[tid] = rkw[tid]; srpw[tid] = rpw[tid]; }

    for (int i = tid; i < 78 * TH2; i += 256) {
        int ly = i / 78, lx = i % 78;
        int gy = oy0 - KR + ly, gx = ox0 - KR + lx;
        wt[ly * SA + lx] = (gy >= 0 && gy < Hh && gx >= 0 && gx < Ww)
                           ? wsrc[baseP + gy * Ww + gx] : 0.f;
    }
    for (int i = tid; i < S2W * S2H2; i += 256) {
        int ly = i / S2W, lx = i % S2W;
        int gy = oy0 - 4 + ly, gx = ox0 - 4 + lx;
        s2[i] = (gy >= 0 && gy < Hh && gx >= 0 && gx < Ww)
                ? pn[baseP + gy * Ww + gx] : 0.f;
    }
    __syncthreads();

    const int colbase = tx * 4;
    const int ry = ty * 2;
    float aA0 = 0.f, aA1 = 0.f, aA2 = 0.f, aA3 = 0.f;
    float aB0 = 0.f, aB1 = 0.f, aB2 = 0.f, aB3 = 0.f;
    for (int i = 0; i < 16; i++) {
        const float4* rp4 = reinterpret_cast<const float4*>(&wt[(ry + i) * SA + colbase]);
        float f[20];
        #pragma unroll
        for (int s5 = 0; s5 < 5; s5++) {
            float4 w4 = rp4[s5];
            f[s5 * 4] = w4.x; f[s5 * 4 + 1] = w4.y; f[s5 * 4 + 2] = w4.z; f[s5 * 4 + 3] = w4.w;
        }
        if (i < 15) {
            const float* krA = kp + (14 - i) * 15;
            #pragma unroll
            for (int j = 0; j < KS; j++) {
                float kv = krA[14 - j];
                aA0 = fmaf(kv, f[j], aA0); aA1 = fmaf(kv, f[j + 1], aA1);
                aA2 = fmaf(kv, f[j + 2], aA2); aA3 = fmaf(kv, f[j + 3], aA3);
            }
        }
        if (i >= 1) {
            const float* krB = kp + (15 - i) * 15;
            #pragma unroll
            for (int j = 0; j < KS; j++) {
                float kv = krB[14 - j];
                aB0 = fmaf(kv, f[j], aB0); aB1 = fmaf(kv, f[j + 1], aB1);
                aB2 = fmaf(kv, f[j + 2], aB2); aB3 = fmaf(kv, f[j + 3], aB3);
            }
        }
    }

    const bool blkInterior = (oy0 >= 2) && (oy0 + BY2 - 1 <= Hh - 3) &&
                             (ox0 >= 2) && (ox0 + BX - 1 <= Ww - 3);
    if (blkInterior) {
        // dual-row 9x9 C stencil (10 window rows serve both output rows)
        for (int t = 0; t < 10; t++) {
            const float4* s4 = reinterpret_cast<const float4*>(&s2[(ry + t) * S2W + colbase]);
            float4 u0 = s4[0], u1 = s4[1], u2 = s4[2];
            float f12[12] = {u0.x,u0.y,u0.z,u0.w,u1.x,u1.y,u1.z,u1.w,u2.x,u2.y,u2.z,u2.w};
            if (t < 9) {
                #pragma unroll
                for (int ox = 0; ox < 9; ox++) {
                    float kv = sC[t * 9 + ox];
                    if (kv != 0.f) {
                        aA0 = fmaf(kv, f12[ox], aA0); aA1 = fmaf(kv, f12[ox + 1], aA1);
                        aA2 = fmaf(kv, f12[ox + 2], aA2); aA3 = fmaf(kv, f12[ox + 3], aA3);
                    }
                }
            }
            if (t >= 1) {
                #pragma unroll
                for (int ox = 0; ox < 9; ox++) {
                    float kv = sC[(t - 1) * 9 + ox];
                    if (kv != 0.f) {
                        aB0 = fmaf(kv, f12[ox], aB0); aB1 = fmaf(kv, f12[ox + 1], aB1);
                        aB2 = fmaf(kv, f12[ox + 2], aB2); aB3 = fmaf(kv, f12[ox + 3], aB3);
                    }
                }
            }
        }
    } else {
        __syncthreads();   // wt (aliased by ph) must be fully consumed first
        for (int m = 0; m < NRK; m++) {
            float wm = srkw[m], rp = srpw[m];
            float coefH = wm * rp * (rp - 1.f);
            if (coefH == 0.f) continue;
            float rmr[25];
            #pragma unroll
            for (int q = 0; q < 25; q++) rmr[q] = rk5[m * 25 + q];
            for (int t = tid; t < PHG2; t += 256) {
                int zy = t / 17, zx0 = (t % 17) * 4;
                int gy = oy0 - 2 + zy, gx0 = ox0 - 2 + zx0;
                float v0 = 0.f, v1 = 0.f, v2 = 0.f, v3 = 0.f;
                #pragma unroll
                for (int a = 0; a < 5; a++) {
                    bool rz = rmr[a*5]==0.f && rmr[a*5+1]==0.f && rmr[a*5+2]==0.f &&
                              rmr[a*5+3]==0.f && rmr[a*5+4]==0.f;
                    if (rz) continue;
                    const float4* s4 = reinterpret_cast<const float4*>(&s2[(zy + a) * S2W + zx0]);
                    float4 u0 = s4[0], u1 = s4[1];
                    float f8[8] = {u0.x,u0.y,u0.z,u0.w,u1.x,u1.y,u1.z,u1.w};
                    #pragma unroll
                    for (int bb = 0; bb < 5; bb++) {
                        float kv = rmr[a * 5 + bb];
                        if (kv != 0.f) {
                            v0 = fmaf(kv, f8[bb], v0); v1 = fmaf(kv, f8[bb+1], v1);
                            v2 = fmaf(kv, f8[bb+2], v2); v3 = fmaf(kv, f8[bb+3], v3);
                        }
                    }
                }
                bool gyin = (gy >= 0 && gy < Hh);
                if (!gyin || gx0     < 0 || gx0     >= Ww) v0 = 0.f;
                if (!gyin || gx0 + 1 < 0 || gx0 + 1 >= Ww) v1 = 0.f;
                if (!gyin || gx0 + 2 < 0 || gx0 + 2 >= Ww) v2 = 0.f;
                if (!gyin || gx0 + 3 < 0 || gx0 + 3 >= Ww) v3 = 0.f;
                *reinterpret_cast<float4*>(&ph[zy * PHW + zx0]) =
                    make_float4(coefH * v0, coefH * v1, coefH * v2, coefH * v3);
            }
            __syncthreads();
            // dual-row 5x5 flipped gather (6 window rows serve both out rows)
            for (int t = 0; t < 6; t++) {
                const float4* q4 = reinterpret_cast<const float4*>(&ph[(ry + t) * PHW + colbase]);
                float4 u0 = q4[0], u1 = q4[1];
                float f8[8] = {u0.x,u0.y,u0.z,u0.w,u1.x,u1.y,u1.z,u1.w};
                if (t < 5) {
                    int fr = 4 - t;
                    #pragma unroll
                    for (int bb = 0; bb < 5; bb++) {
                        float kv = rmr[fr * 5 + (4 - bb)];
                        if (kv != 0.f) {
                            aA0 = fmaf(kv, f8[bb], aA0); aA1 = fmaf(kv, f8[bb+1], aA1);
                            aA2 = fmaf(kv, f8[bb+2], aA2); aA3 = fmaf(kv, f8[bb+3], aA3);
                        }
                    }
                }
                if (t >= 1) {
                    int fr = 5 - t;
                    #pragma unroll
                    for (int bb = 0; bb < 5; bb++) {
                        float kv = rmr[fr * 5 + (4 - bb)];
                        if (kv != 0.f) {
                            aB0 = fmaf(kv, f8[bb], aB0); aB1 = fmaf(kv, f8[bb+1], aB1);
                            aB2 = fmaf(kv, f8[bb+2], aB2); aB3 = fmaf(kv, f8[bb+3], aB3);
                        }
                    }
                }
            }
            __syncthreads();
        }
    }

    const int gx0 = ox0 + colbase;
    float redv = 0.f;
    #pragma unroll
    for (int rr = 0; rr < 2; rr++) {
        const int gy = oy0 + ry + rr;
        float a0 = rr ? aB0 : aA0, a1 = rr ? aB1 : aA1;
        float a2 = rr ? aB2 : aA2, a3 = rr ? aB3 : aA3;
        const int gi = baseP + gy * Ww + gx0;
        *reinterpret_cast<float4*>(&qb[gi]) = make_float4(a0, a1, a2, a3);
        int li = (ry + rr + 4) * S2W + colbase + 4;
        redv += s2[li] * a0 + s2[li + 1] * a1 + s2[li + 2] * a2 + s2[li + 3] * a3;
    }
    float tot = blockReduce(redv, red, tid);
    if (tid == 0) {
        int blk = c * (GXc * GYc2) + blockIdx.y * GXc + blockIdx.x;
        part[((size_t)b * 4 + 1) * PB + blk] = tot;
    }
}

// ---------------------------------------------------------------------
// k_gradL (64x16, unchanged from R11):
// mode 0 (GRAD): r=p=-g; slot2=||r||^2; clip identity for thr!=null;
//   allrp2 && thr==null && interior -> C stencil.
// mode 1 (HESS fallback, only when !allrp2): slot1 over PB entries.
// ---------------------------------------------------------------------
__global__ __launch_bounds__(256)
void k_gradL(const float* __restrict__ kx, const float* __restrict__ wb,
             const float* __restrict__ xg,
             const float* __restrict__ rb, const float* __restrict__ pbuf,
             const float* __restrict__ tgt, const float* __restrict__ thr,
             float* __restrict__ outb,
             float* __restrict__ pout, const float* __restrict__ kernB,
             const float* __restrict__ rks, const float* __restrict__ rkw,
             const float* __restrict__ rpw, const SolveInfo* __restrict__ si,
             float* __restrict__ part, const CgState* __restrict__ st,
             const int* __restrict__ ncg, int iter, int mode)
{
    if (mode == 1 && si->allrp2) return;
    const int pz = blockIdx.z, b = pz / Cn, c = pz % Cn;
    const CgState s = st[b];
    if (mode == 1 && (s.done != 0 || iter >= *ncg)) return;
    __shared__ __align__(16) float wt[SA * THt];    // also reused as ph
    __shared__ __align__(16) float s2[S2W * S2H];
    __shared__ __align__(16) float sC[81];
    __shared__ float rk5[NRK * 25];
    __shared__ float srkw[NRK], srpw[NRK], sthr[NRK];
    __shared__ float red[256];
    float* ph = wt;
    const int tx = threadIdx.x, ty = threadIdx.y, tid = ty * 16 + tx;
    const int ox0 = blockIdx.x * BX, oy0 = blockIdx.y * BY;
    const int baseP = pz * PLANE;
    const float beta = s.beta; const int pf = s.pflag;
    const float* wsrc = si->fastBank ? kx : wb;
    const float* kp = kernB + b * 225;

    for (int i = tid; i < 81; i += 256) sC[i] = si->C[i];
    for (int i = tid; i < NRK * 25; i += 256) rk5[i] = rks[i];
    if (tid < NRK) {
        srkw[tid] = rkw[tid]; srpw[tid] = rpw[tid];
        sthr[tid] = thr ? thr[tid] : 0.f;
    }

    for (int i = tid; i < 78 * THt; i += 256) {
        int ly = i / 78, lx = i % 78;
        int gy = oy0 - KR + ly, gx = ox0 - KR + lx;
        wt[ly * SA + lx] = (gy >= 0 && gy < Hh && gx >= 0 && gx < Ww)
                           ? wsrc[baseP + gy * Ww + gx] : 0.f;
    }
    for (int i = tid; i < S2W * S2H; i += 256) {
        int ly = i / S2W, lx = i % S2W;
        int gy = oy0 - 4 + ly, gx = ox0 - 4 + lx;
        float v = 0.f;
        if (gy >= 0 && gy < Hh && gx >= 0 && gx < Ww) {
            int gi = baseP + gy * Ww + gx;
            if (mode == 0) v = xg[gi];
            else { float rv = rb[gi], pv = pbuf[gi]; v = pf ? fmaf(beta, pv, rv) : pv; }
        }
        s2[i] = v;
    }
    __syncthreads();

    const int colbase = tx * 4;
    float a0 = 0.f, a1 = 0.f, a2 = 0.f, a3 = 0.f;
    for (int i = 0; i < KS; i++) {
        const float4* rp4 = reinterpret_cast<const float4*>(&wt[(ty + i) * SA + colbase]);
        float f[20];
        #pragma unroll
        for (int s5 = 0; s5 < 5; s5++) {
            float4 w4 = rp4[s5];
            f[s5 * 4] = w4.x; f[s5 * 4 + 1] = w4.y; f[s5 * 4 + 2] = w4.z; f[s5 * 4 + 3] = w4.w;
        }
        const float* kr = kp + (14 - i) * 15;
        #pragma unroll
        for (int j = 0; j < KS; j++) {
            float kv = kr[14 - j];
            a0 = fmaf(kv, f[j], a0); a1 = fmaf(kv, f[j + 1], a1);
            a2 = fmaf(kv, f[j + 2], a2); a3 = fmaf(kv, f[j + 3], a3);
        }
    }

    const bool blkInterior = (oy0 >= 2) && (oy0 + BY - 1 <= Hh - 3) &&
                             (ox0 >= 2) && (ox0 + BX - 1 <= Ww - 3);
    if (mode == 0 && si->allrp2 && thr == nullptr && blkInterior) {
        #pragma unroll
        for (int oy = 0; oy < 9; oy++) {
            float cr[9]; bool nz = false;
            #pragma unroll
            for (int ox = 0; ox < 9; ox++) { cr[ox] = sC[oy * 9 + ox]; nz = nz || (cr[ox] != 0.f); }
            if (!nz) continue;
            const float4* s4 = reinterpret_cast<const float4*>(&s2[(ty + oy) * S2W + colbase]);
            float4 u0 = s4[0], u1 = s4[1], u2 = s4[2];
            float f12[12] = {u0.x,u0.y,u0.z,u0.w,u1.x,u1.y,u1.z,u1.w,u2.x,u2.y,u2.z,u2.w};
            #pragma unroll
            for (int ox = 0; ox < 9; ox++) {
                float kv = cr[ox];
                if (kv != 0.f) {
                    a0 = fmaf(kv, f12[ox], a0); a1 = fmaf(kv, f12[ox + 1], a1);
                    a2 = fmaf(kv, f12[ox + 2], a2); a3 = fmaf(kv, f12[ox + 3], a3);
                }
            }
        }
    } else {
        __syncthreads();   // wt fully consumed; ph (alias) may now be written
        for (int m = 0; m < NRK; m++) {
            float wm = srkw[m], rp = srpw[m];
            if (wm == 0.f) continue;
            float rmr[25];
            #pragma unroll
            for (int q = 0; q < 25; q++) rmr[q] = rk5[m * 25 + q];
            const float* tgm = (mode == 1 && tgt)
                ? tgt + ((size_t)(b * NRK + m)) * CHW + (size_t)c * PLANE : nullptr;
            const float coefG = wm * rp;
            const float coefH = wm * rp * (rp - 1.f);
            const float thrm = sthr[m];

            for (int t = tid; t < PHG; t += 256) {
                int zy = t / 17, zx0 = (t % 17) * 4;
                int gy = oy0 - 2 + zy, gx0 = ox0 - 2 + zx0;
                float v0 = 0.f, v1 = 0.f, v2 = 0.f, v3 = 0.f;
                #pragma unroll
                for (int a = 0; a < 5; a++) {
                    bool rz = rmr[a*5]==0.f && rmr[a*5+1]==0.f && rmr[a*5+2]==0.f &&
                              rmr[a*5+3]==0.f && rmr[a*5+4]==0.f;
                    if (rz) continue;
                    const float4* s4 = reinterpret_cast<const float4*>(&s2[(zy + a) * S2W + zx0]);
                    float4 u0 = s4[0], u1 = s4[1];
                    float f8[8] = {u0.x,u0.y,u0.z,u0.w,u1.x,u1.y,u1.z,u1.w};
                    #pragma unroll
                    for (int bb = 0; bb < 5; bb++) {
                        float kv = rmr[a * 5 + bb];
                        if (kv != 0.f) {
                            v0 = fmaf(kv, f8[bb], v0); v1 = fmaf(kv, f8[bb+1], v1);
                            v2 = fmaf(kv, f8[bb+2], v2); v3 = fmaf(kv, f8[bb+3], v3);
                        }
                    }
                }
                bool gyin = (gy >= 0 && gy < Hh);
                float o0 = 0.f, o1 = 0.f, o2 = 0.f, o3 = 0.f;
                #pragma unroll
                for (int j = 0; j < 4; j++) {
                    int gx = gx0 + j;
                    if (!gyin || gx < 0 || gx >= Ww) continue;
                    float v = (j == 0) ? v0 : (j == 1) ? v1 : (j == 2) ? v2 : v3;
                    float o;
                    if (mode == 0) {
                        if (thr) {   // v - shrink(v,thr) == sign(v)*min(|v|,thr)
                            float sgv = (v > 0.f) ? 1.f : ((v < 0.f) ? -1.f : 0.f);
                            v = sgv * fminf(fabsf(v), thrm);
                        }
                        float sg = (v > 0.f) ? 1.f : ((v < 0.f) ? -1.f : 0.f);
                        float av = fabsf(v) + EPSf;
                        o = coefG * sg * ((rp == 2.f) ? av : powf(av, rp - 1.f));
                    } else {
                        float fac = 1.f;
                        if (rp != 2.f) {
                            float vx = 0.f;
                            for (int a = 0; a < 5; a++)
                                for (int bb = 0; bb < 5; bb++) {
                                    int yy = gy - 2 + a, xx = gx - 2 + bb;
                                    if (yy >= 0 && yy < Hh && xx >= 0 && xx < Ww)
                                        vx = fmaf(rmr[a * 5 + bb], xg[baseP + yy * Ww + xx], vx);
                                }
                            if (tgm) vx -= tgm[gy * Ww + gx];
                            fac = powf(fabsf(vx) + EPSf, rp - 2.f);
                        }
                        o = coefH * fac * v;
                    }
                    if (j == 0) o0 = o; else if (j == 1) o1 = o; else if (j == 2) o2 = o; else o3 = o;
                }
                *reinterpret_cast<float4*>(&ph[zy * PHW + zx0]) = make_float4(o0, o1, o2, o3);
            }
            __syncthreads();
            #pragma unroll
            for (int a = 0; a < 5; a++) {
                int fr = 4 - a;
                bool rz = rmr[fr*5]==0.f && rmr[fr*5+1]==0.f && rmr[fr*5+2]==0.f &&
                          rmr[fr*5+3]==0.f && rmr[fr*5+4]==0.f;
                if (rz) continue;
                const float4* q4 = reinterpret_cast<const float4*>(&ph[(ty + a) * PHW + colbase]);
                float4 u0 = q4[0], u1 = q4[1];
                float f8[8] = {u0.x,u0.y,u0.z,u0.w,u1.x,u1.y,u1.z,u1.w};
                #pragma unroll
                for (int bb = 0; bb < 5; bb++) {
                    float kv = rmr[fr * 5 + (4 - bb)];
                    if (kv != 0.f) {
                        a0 = fmaf(kv, f8[bb], a0); a1 = fmaf(kv, f8[bb+1], a1);
                        a2 = fmaf(kv, f8[bb+2], a2); a3 = fmaf(kv, f8[bb+3], a3);
                    }
                }
            }
            __syncthreads();
        }
    }

    const int gi = baseP + (oy0 + ty) * Ww + ox0 + colbase;
    float redv;
    if (mode == 0) {
        float r0v = -a0, r1v = -a1, r2v = -a2, r3v = -a3;
        float4 rv4 = make_float4(r0v, r1v, r2v, r3v);
        *reinterpret_cast<float4*>(&outb[gi]) = rv4;
        *reinterpret_cast<float4*>(&pout[gi]) = rv4;
        redv = r0v * r0v + r1v * r1v + r2v * r2v + r3v * r3v;
    } else {
        *reinterpret_cast<float4*>(&outb[gi]) = make_float4(a0, a1, a2, a3);
        int li = (ty + 4) * S2W + colbase + 4;
        redv = s2[li] * a0 + s2[li + 1] * a1 + s2[li + 2] * a2 + s2[li + 3] * a3;
    }
    float tot = blockReduce(redv, red, tid);
    if (tid == 0) {
        int blk = c * (GXc * GYc) + blockIdx.y * GXc + blockIdx.x;
        int slot = (mode == 0) ? 2 : 1;
        part[((size_t)b * 4 + slot) * PB + blk] = tot;
    }
}

// ---------------------------------------------------------------------
// k_axpy: recompute alpha in-block (no atomics, no fences);
// num over PB2 (conv15 grid); den over PB2 if allrp2 else PB (gradL grid).
// x += alpha*pn ; r -= alpha*q ; slot2 = ||r_new||^2.
// ---------------------------------------------------------------------
__global__ __launch_bounds__(256)
void k_axpy(float4* __restrict__ x, float4* __restrict__ r,
            const float4* __restrict__ pn, const float4* __restrict__ q,
            float* __restrict__ part, const SolveInfo* __restrict__ si,
            const CgState* __restrict__ st,
            const int* __restrict__ ncg, int iter)
{
    const int b = blockIdx.y;
    const CgState s = st[b];
    if (s.done != 0 || iter >= *ncg) return;
    __shared__ float red[256];
    const int tid = threadIdx.x;
    const int nden = si->allrp2 ? PB2 : PB;
    float sn = 0.f, sd = 0.f;
    for (int i = tid; i < PB2; i += 256) sn += part[((size_t)b * 4 + 0) * PB + i];
    for (int i = tid; i < nden; i += 256) sd += part[((size_t)b * 4 + 1) * PB + i];
    float num = blockReduce(sn, red, tid);
    float den = blockReduce(sd, red, tid);
    const float alpha = num / (den + 1e-12f);
    const int idx = b * (CHW / 4) + blockIdx.x * 256 + tid;
    float4 pc = pn[idx], rv = r[idx], qv = q[idx], xv = x[idx];
    xv.x = fmaf(alpha, pc.x, xv.x); xv.y = fmaf(alpha, pc.y, xv.y);
    xv.z = fmaf(alpha, pc.z, xv.z); xv.w = fmaf(alpha, pc.w, xv.w);
    rv.x = fmaf(-alpha, qv.x, rv.x); rv.y = fmaf(-alpha, qv.y, rv.y);
    rv.z = fmaf(-alpha, qv.z, rv.z); rv.w = fmaf(-alpha, qv.w, rv.w);
    x[idx] = xv; r[idx] = rv;
    float nr = rv.x * rv.x + rv.y * rv.y + rv.z * rv.z + rv.w * rv.w;
    float tot = blockReduce(nr, red, tid);
    if (tid == 0) part[((size_t)b * 4 + 2) * PB + blockIdx.x] = tot;
}

// k_fin_iter: mode 0 = CG state init; mode 1 = beta/done update (2 blocks).
__global__ __launch_bounds__(256)
void k_fin_iter(const float* __restrict__ part, CgState* st,
                const int* __restrict__ ncg, int iter, int mode)
{
    const int b = blockIdx.x, tid = threadIdx.x;
    __shared__ float red[256];
    if (mode == 1 && (st[b].done != 0 || iter >= *ncg)) { if (tid == 0) st[b].pflag = 0; return; }
    float s = 0.f;
    for (int i = tid; i < PB; i += 256) s += part[((size_t)b * 4 + 2) * PB + i];
    float nrn = blockReduce(s, red, tid);
    if (tid == 0) {
        if (mode == 0) {
            st[b].rn = nrn; st[b].r0 = nrn; st[b].done = 0; st[b].pflag = 0;
            st[b].beta = 0.f; st[b].alpha = 0.f;
        } else {
            float beta = nrn / (st[b].rn + 1e-20f);
            int conv = (nrn < CGTOL * st[b].r0) ? 1 : 0;
            st[b].beta = beta; st[b].rn = nrn;
            st[b].pflag = conv ? 0 : 1;
            if (conv) st[b].done = 1;
        }
    }
}

// ------------------------- bilateral grid -------------------------
__global__ __launch_bounds__(64)
void k_splat(const float* __restrict__ x, float* __restrict__ grid)
{
    __shared__ float bins[NBn * 2];
    const int tid = threadIdx.y * 8 + threadIdx.x;
    if (tid < NBn * 2) bins[tid] = 0.f;
    __syncthreads();
    const int pz = blockIdx.z;
    const int gy = blockIdx.y, gx = blockIdx.x;
    const int py = gy * 8 + threadIdx.y, px = gx * 8 + threadIdx.x;
    float I = x[(size_t)pz * PLANE + py * Ww + px];
    float Ic = fminf(fmaxf(I, 0.f), 1.f);
    int zi = (int)rintf(Ic * (NBn - 1));
    zi = min(max(zi, 0), NBn - 1);
    atomicAdd(&bins[zi * 2], Ic);
    atomicAdd(&bins[zi * 2 + 1], 1.f);
    __syncthreads();
    if (tid < NBn * 2)
        grid[(size_t)pz * GH * GW * NBn * 2 + ((size_t)gy * GW + gx) * NBn * 2 + tid] = bins[tid];
}

__global__ __launch_bounds__(256)
void k_blur(const float* __restrict__ in, float* __restrict__ out,
            const float* __restrict__ taps, int ntaps, int axis)
{
    const int id = blockIdx.x * 256 + threadIdx.x;
    const int total = Bn * Cn * GH * GW * NBn;
    if (id >= total) return;
    const int z = id % NBn;
    const int x = (id / NBn) % GW;
    const int y = (id / (NBn * GW)) % GH;
    const int p = id / (NBn * GW * GH);
    int coord, lim; long stride;
    if (axis == 0)      { coord = y; lim = GH;  stride = (long)GW * NBn * 2; }
    else if (axis == 1) { coord = x; lim = GW;  stride = NBn * 2; }
    else                { coord = z; lim = NBn; stride = 2; }
    const long base = (((long)(p * GH + y) * GW + x) * NBn + z) * 2;
    const int r = ntaps / 2;
    float a0 = 0.f, a1 = 0.f;
    for (int t = 0; t < ntaps; t++) {
        int cc = coord + t - r;
        if (cc < 0 || cc >= lim) continue;
        float w = taps[t];
        long ofs = base + (long)(cc - coord) * stride;
        a0 = fmaf(w, in[ofs], a0);
        a1 = fmaf(w, in[ofs + 1], a1);
    }
    out[base] = a0; out[base + 1] = a1;
}

__global__ __launch_bounds__(256)
void k_slice(const float* __restrict__ xin, const float* __restrict__ grid,
             float* __restrict__ xout)
{
    const int pz = blockIdx.z;
    const int id = blockIdx.x * 256 + threadIdx.x;
    const int py = id / Ww, px = id % Ww;
    float I = xin[(size_t)pz * PLANE + id];
    float Ic = fminf(fmaxf(I, 0.f), 1.f);
    float yf = (float)py / SS, xf = (float)px / SS, zf = Ic * (NBn - 1);
    int y0 = min(max((int)floorf(yf), 0), GH - 1); int y1 = min(y0 + 1, GH - 1);
    float wy = fminf(fmaxf(yf - (float)y0, 0.f), 1.f);
    int x0 = min(max((int)floorf(xf), 0), GW - 1); int x1 = min(x0 + 1, GW - 1);
    float wx = fminf(fmaxf(xf - (float)x0, 0.f), 1.f);
    int z0 = min(max((int)floorf(zf), 0), NBn - 1); int z1 = min(z0 + 1, NBn - 1);
    float wz = fminf(fmaxf(zf - (float)z0, 0.f), 1.f);
    const float* gp = grid + (size_t)pz * GH * GW * NBn * 2;
    const int   ys[2] = { y0, y1 };  const float wys[2] = { 1.f - wy, wy };
    const int   xs[2] = { x0, x1 };  const float wxs[2] = { 1.f - wx, wx };
    const int   zs[2] = { z0, z1 };  const float wzs[2] = { 1.f - wz, wz };
    float a0 = 0.f, a1 = 0.f;
    for (int iy = 0; iy < 2; iy++)
        for (int ix = 0; ix < 2; ix++)
            for (int iz = 0; iz < 2; iz++) {
                float w = wys[iy] * wxs[ix] * wzs[iz];
                size_t idx = (((size_t)ys[iy] * GW + xs[ix]) * NBn + zs[iz]) * 2;
                a0 = fmaf(w, gp[idx], a0);
                a1 = fmaf(w, gp[idx + 1], a1);
            }
    xout[(size_t)pz * PLANE + id] = a0 / (a1 + 1e-8f);
}

// k_prior: builds reg targets; only needed for the !allrp2 fallback Hessian.
__global__ __launch_bounds__(256)
void k_prior(const float* __restrict__ x, float* __restrict__ tgt,
             const float* __restrict__ rks, const float* __restrict__ thr,
             const SolveInfo* __restrict__ si)
{
    if (si->allrp2) return;
    const int pz = blockIdx.z, b = pz / Cn, c = pz % Cn;
    __shared__ float xl[24 * 24];
    __shared__ float rkk[NRK * 25];
    __shared__ float sthr[NRK];
    const int tx = threadIdx.x, ty = threadIdx.y, tid = ty * 16 + tx;
    const int ox0 = blockIdx.x * 16, oy0 = blockIdx.y * 16;
    const int baseP = pz * PLANE;
    for (int i = tid; i < NRK * 25; i += 256) rkk[i] = rks[i];
    if (tid < NRK) sthr[tid] = thr[tid];
    for (int i = tid; i < 24 * 24; i += 256) {
        int ly = i / 24, lx = i % 24;
        int gy = oy0 - 2 + ly, gx = ox0 - 2 + lx;
        xl[i] = (gy >= 0 && gy < Hh && gx >= 0 && gx < Ww) ? x[baseP + gy * Ww + gx] : 0.f;
    }
    __syncthreads();
    const int pix = (oy0 + ty) * Ww + (ox0 + tx);
    for (int m = 0; m < NRK; m++) {
        const float* rm = &rkk[m * 25];
        float v = 0.f;
        #pragma unroll
        for (int a = 0; a < 5; a++)
            #pragma unroll
            for (int bb = 0; bb < 5; bb++)
                v = fmaf(rm[a * 5 + bb], xl[(ty + a) * 24 + (tx + bb)], v);
        float sg = (v > 0.f) ? 1.f : ((v < 0.f) ? -1.f : 0.f);
        tgt[((size_t)(b * NRK + m)) * CHW + (size_t)c * PLANE + pix] =
            sg * fmaxf(fabsf(v) - sthr[m], 0.f);
    }
}

// ------------------------------ host ------------------------------
extern "C" void kernel_launch(void* const* d_in, const int* in_sizes, int n_in,
                              void* d_out, int out_size, void* d_ws, size_t ws_size,
                              hipStream_t stream)
{
    const float* blurred = (const float*)d_in[0];
    const float* kern    = (const float*)d_in[1];
    const float* dks     = (const float*)d_in[2];
    const float* dkw     = (const float*)d_in[3];
    const float* rks     = (const float*)d_in[4];
    const float* rkw     = (const float*)d_in[5];
    const float* rpw     = (const float*)d_in[6];
    const float* fs      = (const float*)d_in[7];
    const float* fr      = (const float*)d_in[8];
    const float* thr     = (const float*)d_in[9];
    const int*   ncg     = (const int*)d_in[10];
    (void)in_sizes; (void)n_in; (void)out_size; (void)ws_size;

    float* w = (float*)d_ws;
    size_t off = 0;
    auto alloc = [&](size_t n) { float* p = w + off; off += n; return p; };
    float* xb    = alloc((size_t)Bn * CHW);
    float* pbufA = alloc((size_t)Bn * CHW);
    float* pbufB = alloc((size_t)Bn * CHW);
    float* rbuf  = alloc((size_t)Bn * CHW);
    float* kx    = alloc((size_t)Bn * CHW);
    float* wb    = alloc((size_t)Bn * CHW);
    float* qb    = alloc((size_t)Bn * CHW);
    float* tg    = alloc((size_t)Bn * NRK * CHW);
    float* g0    = alloc((size_t)Bn * Cn * GH * GW * NBn * 2);
    float* g1    = alloc((size_t)Bn * Cn * GH * GW * NBn * 2);
    float* part  = alloc((size_t)Bn * 4 * PB);
    CgState* st = (CgState*)(w + off); off += Bn * 8;
    SolveInfo* sinf = (SolveInfo*)(w + off); off += 2 * ((sizeof(SolveInfo) + 3) / 4);
    float* xout = (float*)d_out;   // solve-2 x lives in d_out (no final memcpy)

    dim3 tb(16, 16);
    dim3 grd(GXc, GYc, Bn * Cn);    // 64x16 tiles (gradL, bank)
    dim3 grd2(GXc, GYc2, Bn * Cn);  // 64x32 tiles (conv15, hess)

    k_comp<<<2, 128, 0, stream>>>(dkw, dks, rkw, rpw, rks, sinf);

    auto solve = [&](int idx, float* xcur, const float* tgt_i, const float* thr_i,
                     int initmode) {
        const float* dks_i = dks + (size_t)idx * NDK * 25;
        const float* dkw_i = dkw + (size_t)idx * NDK;
        const float* rks_i = rks + (size_t)idx * NRK * 25;
        const float* rkw_i = rkw + (size_t)idx * NRK;
        const float* rpw_i = rpw + (size_t)idx * NRK;
        const SolveInfo* si = sinf + idx;
        k_conv15<<<grd2, tb, 0, stream>>>(initmode == 0 ? blurred : xcur, nullptr, nullptr,
                                          initmode == 0 ? xcur : nullptr, blurred, kx, kern,
                                          nullptr, si, st, ncg, 0, initmode == 0 ? 0 : 3);
        k_bank<<<grd, tb, 0, stream>>>(kx, wb, dks_i, dkw_i, si, st, ncg, 0, 0);
        k_gradL<<<grd, tb, 0, stream>>>(kx, wb, xcur, nullptr, nullptr, tgt_i, thr_i,
                                        rbuf, pbufA, kern,
                                        rks_i, rkw_i, rpw_i, si, part, st, ncg, 0, 0);
        k_fin_iter<<<Bn, 256, 0, stream>>>(part, st, ncg, 0, 0);
        float* pcur = pbufA;
        float* pnxt = pbufB;
        for (int i = 0; i < NITER; i++) {
            k_conv15<<<grd2, tb, 0, stream>>>(nullptr, rbuf, pcur, pnxt, nullptr, kx, kern,
                                              part, si, st, ncg, i, 2);
            k_bank<<<grd, tb, 0, stream>>>(kx, wb, dks_i, dkw_i, si, st, ncg, i, 1);
            k_hess<<<grd2, tb, 0, stream>>>(kx, wb, pnxt, qb, kern,
                                            rks_i, rkw_i, rpw_i, si, part, st, ncg, i);
            k_gradL<<<grd, tb, 0, stream>>>(kx, wb, xcur, rbuf, pnxt, tgt_i, thr_i, qb, nullptr,
                                            kern, rks_i, rkw_i, rpw_i, si, part, st, ncg, i, 1);
            k_axpy<<<dim3(PB, Bn), 256, 0, stream>>>((float4*)xcur, (float4*)rbuf,
                                                     (const float4*)pnxt, (const float4*)qb,
                                                     part, si, st, ncg, i);
            k_fin_iter<<<Bn, 256, 0, stream>>>(part, st, ncg, i, 1);
            float* tswap = pcur; pcur = pnxt; pnxt = tswap;
        }
    };

    // CG solve 1 (idx 0, zero reg targets, x0 = blurred, x buffer = xb)
    solve(0, xb, nullptr, nullptr, 0);

    // bilateral grid stage (stage 0): xb -> d_out
    dim3 sb(8, 8), sg(GW, GH, Bn * Cn);
    k_splat<<<sg, sb, 0, stream>>>(xb, g0);
    const int totalg = Bn * Cn * GH * GW * NBn;
    k_blur<<<(totalg + 255) / 256, 256, 0, stream>>>(g0, g1, fs, 11, 0);
    k_blur<<<(totalg + 255) / 256, 256, 0, stream>>>(g1, g0, fs, 11, 1);
    k_blur<<<(totalg + 255) / 256, 256, 0, stream>>>(g0, g1, fr, 5, 2);
    k_slice<<<dim3(PLANE / 256, 1, Bn * Cn), 256, 0, stream>>>(xb, g1, xout);

    // shrinkage prior -> reg targets (only materialized for !allrp2 fallback)
    k_prior<<<dim3(Ww / 16, Hh / 16, Bn * Cn), tb, 0, stream>>>(xout, tg, rks + NRK * 25, thr,
                                                                sinf + 1);

    // CG solve 2 (idx 1, clip identity, x buffer = d_out — result stays there)
    solve(1, xout, tg, thr, 1);
}

// Round 14
// 1318.961 us; speedup vs baseline: 1.1289x; 1.1289x over previous
//
#include <hip/hip_runtime.h>

// ---------------- problem constants (match setup_inputs) ----------------
constexpr int Bn = 2, Cn = 3, Hh = 512, Ww = 512;
constexpr int KS = 15, KR = 7;          // PSF kernel
constexpr int NDK = 6, NRK = 5;         // data / reg bank sizes (5x5, r=2)
constexpr int GH = 64, GW = 64, NBn = 9, SS = 8;  // bilateral grid
constexpr float EPSf = 1e-8f;
constexpr float CGTOL = 1e-4f;
constexpr int PLANE = Hh * Ww;
constexpr int CHW = Cn * PLANE;
constexpr int BX = 64, BY = 16;         // conv output tile (4 px/thread in x)
constexpr int GXc = Ww / BX, GYc = Hh / BY;   // 8 x 32
constexpr int PB = GXc * GYc * Cn;      // 768 partial-blocks per batch
constexpr int SA = 80, THt = 30;        // 15x15 halo tile: 78x30 data, stride 80
constexpr int S2W = 72, S2H = 24;       // 5x5 src tile (halo 4): 72x24
constexpr int PHW = 68, PHH = 20;       // 5x5 mid tile (halo 2): 68x20
constexpr int PHG = (PHW / 4) * PHH;    // 340 float4-groups in mid tile
constexpr int NITER = 5;

struct CgState { float alpha, beta, rn, r0; int done, pflag; int pad0, pad1; };

// runtime-derived solve info (computed on device by k_comp; keeps kernel generic)
struct SolveInfo {
    int fastBank;      // all active data kernels are single-nonzero (delta)
    int allrp2;        // reg Hessian/grad reducible to composite stencil
    int nd;
    int pad;
    float sctot;
    float dsc[NDK];
    int ddy[NDK], ddx[NDK];
    float C[81];       // composite reg stencil (coef-weighted autocorrelation)
};

__device__ __forceinline__ float blockReduce(float v, float* red, int tid) {
    red[tid] = v; __syncthreads();
    for (int s = 128; s > 0; s >>= 1) { if (tid < s) red[tid] += red[tid + s]; __syncthreads(); }
    float r = red[0]; __syncthreads();
    return r;
}

// ---------------------------------------------------------------------
// k_comp: build SolveInfo for each solve index (2 blocks).
// ---------------------------------------------------------------------
__global__ __launch_bounds__(128)
void k_comp(const float* __restrict__ dkw, const float* __restrict__ dks,
            const float* __restrict__ rkw, const float* __restrict__ rpw,
            const float* __restrict__ rks, SolveInfo* si)
{
    const int idx = blockIdx.x;
    SolveInfo* s = si + idx;
    const float* dkw_i = dkw + idx * NDK;
    const float* dks_i = dks + (size_t)idx * NDK * 25;
    const float* rkw_i = rkw + idx * NRK;
    const float* rpw_i = rpw + idx * NRK;
    const float* rks_i = rks + (size_t)idx * NRK * 25;
    const int t = threadIdx.x;
    if (t < 81) {
        int oy = t / 9 - 4, ox = t % 9 - 4;
        float acc = 0.f;
        for (int m = 0; m < NRK; m++) {
            float wm = rkw_i[m], rp = rpw_i[m];
            float ch = wm * rp * (rp - 1.f);
            if (ch == 0.f) continue;
            for (int ay = 0; ay < 5; ay++)
                for (int ax = 0; ax < 5; ax++) {
                    int by = ay - oy, bx = ax - ox;
                    if (by < 0 || by >= 5 || bx < 0 || bx >= 5) continue;
                    acc += ch * rks_i[m * 25 + ay * 5 + ax] * rks_i[m * 25 + by * 5 + bx];
                }
        }
        s->C[t] = acc;
    }
    if (t == 81) {
        int fast = 1, nd = 0; float tot = 0.f;
        for (int n = 0; n < NDK; n++) {
            if (dkw_i[n] == 0.f) continue;
            int cntz = 0, pos = -1;
            for (int q = 0; q < 25; q++) if (dks_i[n * 25 + q] != 0.f) { cntz++; pos = q; }
            if (cntz > 1) fast = 0;
            if (cntz == 1 && nd < NDK) {
                float v = dks_i[n * 25 + pos];
                s->dsc[nd] = 2.f * dkw_i[n] * v * v;
                s->ddy[nd] = pos / 5 - 2; s->ddx[nd] = pos % 5 - 2;
                tot += s->dsc[nd]; nd++;
            }
        }
        s->fastBank = fast; s->nd = fast ? nd : 0; s->sctot = tot;
    }
    if (t == 82) {
        int ok = 1;
        for (int m = 0; m < NRK; m++) {
            float wm = rkw_i[m], rp = rpw_i[m];
            if (wm != 0.f && rp != 2.f && wm * rp * (rp - 1.f) != 0.f) ok = 0;
        }
        s->allrp2 = ok;
    }
}

// ---------------------------------------------------------------------
// k_conv15: 15x15 correlation, 64x16 tile, 4 px/thread.
// Kernel taps read via block-uniform global loads (scalar path, no LDS).
// mode 0: v = src, copy v -> aux2 (interior), out = corr(v) - sub  (no skip)
// mode 3: v = src,                            out = corr(v) - sub  (no skip)
// mode 2: v = p_cur = pflag ? r + beta*p : p ; persist p_cur -> aux2 (interior);
//         out = corr(v); num -> slot0
// When si->fastBank: output scaled by the data-bank composite (delta masks).
// ---------------------------------------------------------------------
__global__ __launch_bounds__(256)
void k_conv15(const float* __restrict__ src, const float* __restrict__ rb,
              const float* __restrict__ pbuf, float* __restrict__ aux2,
              const float* __restrict__ sub, float* __restrict__ out,
              const float* __restrict__ kernB, float* __restrict__ part,
              const SolveInfo* __restrict__ si,
              const CgState* __restrict__ st, const int* __restrict__ ncg,
              int iter, int mode)
{
    const int pz = blockIdx.z, b = pz / Cn, c = pz % Cn;
    const CgState s = st[b];
    if (mode == 2 && (s.done != 0 || iter >= *ncg)) return;
    __shared__ __align__(16) float tile[SA * THt];
    __shared__ float red[256];
    const int tx = threadIdx.x, ty = threadIdx.y, tid = ty * 16 + tx;
    const int ox0 = blockIdx.x * BX, oy0 = blockIdx.y * BY;
    const int baseP = pz * PLANE;
    const float beta = s.beta; const int pf = s.pflag;
    const float* kp = kernB + b * 225;

    float nm = 0.f;
    for (int i = tid; i < 78 * THt; i += 256) {
        int ly = i / 78, lx = i % 78;
        int gy = oy0 - KR + ly, gx = ox0 - KR + lx;
        float v = 0.f;
        if (gy >= 0 && gy < Hh && gx >= 0 && gx < Ww) {
            int gi = baseP + gy * Ww + gx;
            if (mode == 2) {
                float rv = rb[gi], pv = pbuf[gi];
                v = pf ? fmaf(beta, pv, rv) : pv;
                if (ly >= KR && ly < KR + BY && lx >= KR && lx < KR + BX) {
                    nm = fmaf(rv, v, nm);
                    aux2[gi] = v;            // persist p_cur (own tile only)
                }
            } else {
                v = src[gi];
                if (mode == 0 && ly >= KR && ly < KR + BY && lx >= KR && lx < KR + BX)
                    aux2[gi] = v;
            }
        }
        tile[ly * SA + lx] = v;
    }
    __syncthreads();

    const int colbase = tx * 4;
    float a0 = 0.f, a1 = 0.f, a2 = 0.f, a3 = 0.f;
    for (int i = 0; i < KS; i++) {
        const float4* rp4 = reinterpret_cast<const float4*>(&tile[(ty + i) * SA + colbase]);
        float f[20];
        #pragma unroll
        for (int s5 = 0; s5 < 5; s5++) {
            float4 w4 = rp4[s5];
            f[s5 * 4] = w4.x; f[s5 * 4 + 1] = w4.y; f[s5 * 4 + 2] = w4.z; f[s5 * 4 + 3] = w4.w;
        }
        const float* kr = kp + i * 15;   // block-uniform -> scalar loads
        #pragma unroll
        for (int j = 0; j < KS; j++) {
            float kv = kr[j];
            a0 = fmaf(kv, f[j], a0); a1 = fmaf(kv, f[j + 1], a1);
            a2 = fmaf(kv, f[j + 2], a2); a3 = fmaf(kv, f[j + 3], a3);
        }
    }
    const int gi = baseP + (oy0 + ty) * Ww + ox0 + colbase;
    if (sub) {
        float4 sv = *reinterpret_cast<const float4*>(&sub[gi]);
        a0 -= sv.x; a1 -= sv.y; a2 -= sv.z; a3 -= sv.w;
    }
    if (si->fastBank) {
        const int gy = oy0 + ty, gx0 = ox0 + colbase;
        if (gy >= 2 && gy <= Hh - 3 && gx0 >= 2 && gx0 + 3 <= Ww - 3) {
            float sc = si->sctot;
            a0 *= sc; a1 *= sc; a2 *= sc; a3 *= sc;
        } else {
            float m0 = 0.f, m1 = 0.f, m2 = 0.f, m3 = 0.f;
            int ndl = si->nd;
            for (int n = 0; n < ndl; n++) {
                float sc = si->dsc[n]; int dy = si->ddy[n], dx = si->ddx[n];
                if (gy - dy < 0 || gy - dy >= Hh) continue;
                if (gx0     - dx >= 0 && gx0     - dx < Ww) m0 += sc;
                if (gx0 + 1 - dx >= 0 && gx0 + 1 - dx < Ww) m1 += sc;
                if (gx0 + 2 - dx >= 0 && gx0 + 2 - dx < Ww) m2 += sc;
                if (gx0 + 3 - dx >= 0 && gx0 + 3 - dx < Ww) m3 += sc;
            }
            a0 *= m0; a1 *= m1; a2 *= m2; a3 *= m3;
        }
    }
    *reinterpret_cast<float4*>(&out[gi]) = make_float4(a0, a1, a2, a3);
    if (mode == 2) {
        float tot = blockReduce(nm, red, tid);
        if (tid == 0) {
            int blk = c * (GXc * GYc) + blockIdx.y * GXc + blockIdx.x;
            part[((size_t)b * 4 + 0) * PB + blk] = tot;
        }
    }
}

// ---------------------------------------------------------------------
// k_bank: generic data-bank composite (only when !fastBank).
// ---------------------------------------------------------------------
__global__ __launch_bounds__(256)
void k_bank(const float* __restrict__ sbuf, float* __restrict__ tbuf,
            const float* __restrict__ dks, const float* __restrict__ dkw,
            const SolveInfo* __restrict__ si,
            const CgState* __restrict__ st, const int* __restrict__ ncg,
            int iter, int mode)
{
    if (si->fastBank) return;
    const int pz = blockIdx.z, b = pz / Cn;
    if (mode == 1 && (st[b].done != 0 || iter >= *ncg)) return;
    __shared__ __align__(16) float sl[S2W * S2H];
    __shared__ __align__(16) float dl[PHW * PHH];
    __shared__ float dkk[NDK * 25];
    __shared__ float dww[NDK];
    const int tx = threadIdx.x, ty = threadIdx.y, tid = ty * 16 + tx;
    const int ox0 = blockIdx.x * BX, oy0 = blockIdx.y * BY;
    const int baseP = pz * PLANE;
    const int colbase = tx * 4;
    for (int i = tid; i < NDK * 25; i += 256) dkk[i] = dks[i];
    if (tid < NDK) dww[tid] = dkw[tid];
    for (int i = tid; i < S2W * S2H; i += 256) {
        int ly = i / S2W, lx = i % S2W;
        int gy = oy0 - 4 + ly, gx = ox0 - 4 + lx;
        sl[i] = (gy >= 0 && gy < Hh && gx >= 0 && gx < Ww) ? sbuf[baseP + gy * Ww + gx] : 0.f;
    }
    __syncthreads();
    float t0 = 0.f, t1 = 0.f, t2 = 0.f, t3 = 0.f;
    for (int n = 0; n < NDK; n++) {
        float wn = 2.f * dww[n];
        if (wn == 0.f) continue;
        float dnr[25];
        #pragma unroll
        for (int q = 0; q < 25; q++) dnr[q] = dkk[n * 25 + q];
        for (int t = tid; t < PHG; t += 256) {
            int zy = t / 17, zx0 = (t % 17) * 4;
            int gy = oy0 - 2 + zy, gx0 = ox0 - 2 + zx0;
            float v0 = 0.f, v1 = 0.f, v2 = 0.f, v3 = 0.f;
            #pragma unroll
            for (int a = 0; a < 5; a++) {
                bool rz = dnr[a*5]==0.f && dnr[a*5+1]==0.f && dnr[a*5+2]==0.f &&
                          dnr[a*5+3]==0.f && dnr[a*5+4]==0.f;
                if (rz) continue;
                const float4* s4 = reinterpret_cast<const float4*>(&sl[(zy + a) * S2W + zx0]);
                float4 u0 = s4[0], u1 = s4[1];
                float f8[8] = {u0.x,u0.y,u0.z,u0.w,u1.x,u1.y,u1.z,u1.w};
                #pragma unroll
                for (int bb = 0; bb < 5; bb++) {
                    float kv = dnr[a * 5 + bb];
                    if (kv != 0.f) {
                        v0 = fmaf(kv, f8[bb], v0); v1 = fmaf(kv, f8[bb+1], v1);
                        v2 = fmaf(kv, f8[bb+2], v2); v3 = fmaf(kv, f8[bb+3], v3);
                    }
                }
            }
            bool gyin = (gy >= 0 && gy < Hh);
            if (!gyin || gx0     < 0 || gx0     >= Ww) v0 = 0.f;
            if (!gyin || gx0 + 1 < 0 || gx0 + 1 >= Ww) v1 = 0.f;
            if (!gyin || gx0 + 2 < 0 || gx0 + 2 >= Ww) v2 = 0.f;
            if (!gyin || gx0 + 3 < 0 || gx0 + 3 >= Ww) v3 = 0.f;
            *reinterpret_cast<float4*>(&dl[zy * PHW + zx0]) = make_float4(v0, v1, v2, v3);
        }
        __syncthreads();
        float c0 = 0.f, c1 = 0.f, c2 = 0.f, c3 = 0.f;
        #pragma unroll
        for (int a = 0; a < 5; a++) {
            int fr = 4 - a;
            bool rz = dnr[fr*5]==0.f && dnr[fr*5+1]==0.f && dnr[fr*5+2]==0.f &&
                      dnr[fr*5+3]==0.f && dnr[fr*5+4]==0.f;
            if (rz) continue;
            const float4* q4 = reinterpret_cast<const float4*>(&dl[(ty + a) * PHW + colbase]);
            float4 u0 = q4[0], u1 = q4[1];
            float f8[8] = {u0.x,u0.y,u0.z,u0.w,u1.x,u1.y,u1.z,u1.w};
            #pragma unroll
            for (int bb = 0; bb < 5; bb++) {
                float kv = dnr[fr * 5 + (4 - bb)];
                if (kv != 0.f) {
                    c0 = fmaf(kv, f8[bb], c0); c1 = fmaf(kv, f8[bb+1], c1);
                    c2 = fmaf(kv, f8[bb+2], c2); c3 = fmaf(kv, f8[bb+3], c3);
                }
            }
        }
        t0 = fmaf(wn, c0, t0); t1 = fmaf(wn, c1, t1);
        t2 = fmaf(wn, c2, t2); t3 = fmaf(wn, c3, t3);
        __syncthreads();
    }
    const int gi = baseP + (oy0 + ty) * Ww + ox0 + colbase;
    *reinterpret_cast<float4*>(&tbuf[gi]) = make_float4(t0, t1, t2, t3);
}

// ---------------------------------------------------------------------
// k_hess (hot path, allrp2): q = corr15T(w) + reg Hessian term; p from pn.
// Interior blocks: composite 9x9 C stencil. Border blocks: block-uniform
// two-pass LDS path (ph aliased into dead wt). slot1 = sum p_cur*q.
// ---------------------------------------------------------------------
__global__ __launch_bounds__(256)
void k_hess(const float* __restrict__ kx, const float* __restrict__ wb,
            const float* __restrict__ pn,
            float* __restrict__ qb, const float* __restrict__ kernB,
            const float* __restrict__ rks, const float* __restrict__ rkw,
            const float* __restrict__ rpw, const SolveInfo* __restrict__ si,
            float* __restrict__ part, const CgState* __restrict__ st,
            const int* __restrict__ ncg, int iter)
{
    if (!si->allrp2) return;
    const int pz = blockIdx.z, b = pz / Cn, c = pz % Cn;
    const CgState s = st[b];
    if (s.done != 0 || iter >= *ncg) return;
    __shared__ __align__(16) float wt[SA * THt];     // also reused as ph
    __shared__ __align__(16) float s2[S2W * S2H];
    __shared__ __align__(16) float sC[81];
    __shared__ float rk5[NRK * 25];
    __shared__ float srkw[NRK], srpw[NRK];
    __shared__ float red[256];
    float* ph = wt;                                  // alias: wt dead after corr15T
    const int tx = threadIdx.x, ty = threadIdx.y, tid = ty * 16 + tx;
    const int ox0 = blockIdx.x * BX, oy0 = blockIdx.y * BY;
    const int baseP = pz * PLANE;
    const float* wsrc = si->fastBank ? kx : wb;
    const float* kp = kernB + b * 225;

    for (int i = tid; i < 81; i += 256) sC[i] = si->C[i];
    for (int i = tid; i < NRK * 25; i += 256) rk5[i] = rks[i];
    if (tid < NRK) { srkw[tid] = rkw[tid]; srpw[tid] = rpw[tid]; }

    for (int i = tid; i < 78 * THt; i += 256) {
        int ly = i / 78, lx = i % 78;
        int gy = oy0 - KR + ly, gx = ox0 - KR + lx;
        wt[ly * SA + lx] = (gy >= 0 && gy < Hh && gx >= 0 && gx < Ww)
                           ? wsrc[baseP + gy * Ww + gx] : 0.f;
    }
    for (int i = tid; i < S2W * S2H; i += 256) {
        int ly = i / S2W, lx = i % S2W;
        int gy = oy0 - 4 + ly, gx = ox0 - 4 + lx;
        s2[i] = (gy >= 0 && gy < Hh && gx >= 0 && gx < Ww)
                ? pn[baseP + gy * Ww + gx] : 0.f;
    }
    __syncthreads();

    const int colbase = tx * 4;
    float a0 = 0.f, a1 = 0.f, a2 = 0.f, a3 = 0.f;
    for (int i = 0; i < KS; i++) {
        const float4* rp4 = reinterpret_cast<const float4*>(&wt[(ty + i) * SA + colbase]);
        float f[20];
        #pragma unroll
        for (int s5 = 0; s5 < 5; s5++) {
            float4 w4 = rp4[s5];
            f[s5 * 4] = w4.x; f[s5 * 4 + 1] = w4.y; f[s5 * 4 + 2] = w4.z; f[s5 * 4 + 3] = w4.w;
        }
        const float* kr = kp + (14 - i) * 15;   // flipped row, block-uniform
        #pragma unroll
        for (int j = 0; j < KS; j++) {
            float kv = kr[14 - j];
            a0 = fmaf(kv, f[j], a0); a1 = fmaf(kv, f[j + 1], a1);
            a2 = fmaf(kv, f[j + 2], a2); a3 = fmaf(kv, f[j + 3], a3);
        }
    }

    const bool blkInterior = (oy0 >= 2) && (oy0 + BY - 1 <= Hh - 3) &&
                             (ox0 >= 2) && (ox0 + BX - 1 <= Ww - 3);
    if (blkInterior) {
        #pragma unroll
        for (int oy = 0; oy < 9; oy++) {
            float cr[9]; bool nz = false;
            #pragma unroll
            for (int ox = 0; ox < 9; ox++) { cr[ox] = sC[oy * 9 + ox]; nz = nz || (cr[ox] != 0.f); }
            if (!nz) continue;
            const float4* s4 = reinterpret_cast<const float4*>(&s2[(ty + oy) * S2W + colbase]);
            float4 u0 = s4[0], u1 = s4[1], u2 = s4[2];
            float f12[12] = {u0.x,u0.y,u0.z,u0.w,u1.x,u1.y,u1.z,u1.w,u2.x,u2.y,u2.z,u2.w};
            #pragma unroll
            for (int ox = 0; ox < 9; ox++) {
                float kv = cr[ox];
                if (kv != 0.f) {
                    a0 = fmaf(kv, f12[ox], a0); a1 = fmaf(kv, f12[ox + 1], a1);
                    a2 = fmaf(kv, f12[ox + 2], a2); a3 = fmaf(kv, f12[ox + 3], a3);
                }
            }
        }
    } else {
        __syncthreads();   // wt (aliased by ph) must be fully consumed first
        for (int m = 0; m < NRK; m++) {
            float wm = srkw[m], rp = srpw[m];
            float coefH = wm * rp * (rp - 1.f);
            if (coefH == 0.f) continue;
            float rmr[25];
            #pragma unroll
            for (int q = 0; q < 25; q++) rmr[q] = rk5[m * 25 + q];
            for (int t = tid; t < PHG; t += 256) {
                int zy = t / 17, zx0 = (t % 17) * 4;
                int gy = oy0 - 2 + zy, gx0 = ox0 - 2 + zx0;
                float v0 = 0.f, v1 = 0.f, v2 = 0.f, v3 = 0.f;
                #pragma unroll
                for (int a = 0; a < 5; a++) {
                    bool rz = rmr[a*5]==0.f && rmr[a*5+1]==0.f && rmr[a*5+2]==0.f &&
                              rmr[a*5+3]==0.f && rmr[a*5+4]==0.f;
                    if (rz) continue;
                    const float4* s4 = reinterpret_cast<const float4*>(&s2[(zy + a) * S2W + zx0]);
                    float4 u0 = s4[0], u1 = s4[1];
                    float f8[8] = {u0.x,u0.y,u0.z,u0.w,u1.x,u1.y,u1.z,u1.w};
                    #pragma unroll
                    for (int bb = 0; bb < 5; bb++) {
                        float kv = rmr[a * 5 + bb];
                        if (kv != 0.f) {
                            v0 = fmaf(kv, f8[bb], v0); v1 = fmaf(kv, f8[bb+1], v1);
                            v2 = fmaf(kv, f8[bb+2], v2); v3 = fmaf(kv, f8[bb+3], v3);
                        }
                    }
                }
                bool gyin = (gy >= 0 && gy < Hh);
                if (!gyin || gx0     < 0 || gx0     >= Ww) v0 = 0.f;
                if (!gyin || gx0 + 1 < 0 || gx0 + 1 >= Ww) v1 = 0.f;
                if (!gyin || gx0 + 2 < 0 || gx0 + 2 >= Ww) v2 = 0.f;
                if (!gyin || gx0 + 3 < 0 || gx0 + 3 >= Ww) v3 = 0.f;
                *reinterpret_cast<float4*>(&ph[zy * PHW + zx0]) =
                    make_float4(coefH * v0, coefH * v1, coefH * v2, coefH * v3);
            }
            __syncthreads();
            #pragma unroll
            for (int a = 0; a < 5; a++) {
                int fr = 4 - a;
                bool rz = rmr[fr*5]==0.f && rmr[fr*5+1]==0.f && rmr[fr*5+2]==0.f &&
                          rmr[fr*5+3]==0.f && rmr[fr*5+4]==0.f;
                if (rz) continue;
                const float4* q4 = reinterpret_cast<const float4*>(&ph[(ty + a) * PHW + colbase]);
                float4 u0 = q4[0], u1 = q4[1];
                float f8[8] = {u0.x,u0.y,u0.z,u0.w,u1.x,u1.y,u1.z,u1.w};
                #pragma unroll
                for (int bb = 0; bb < 5; bb++) {
                    float kv = rmr[fr * 5 + (4 - bb)];
                    if (kv != 0.f) {
                        a0 = fmaf(kv, f8[bb], a0); a1 = fmaf(kv, f8[bb+1], a1);
                        a2 = fmaf(kv, f8[bb+2], a2); a3 = fmaf(kv, f8[bb+3], a3);
                    }
                }
            }
            __syncthreads();
        }
    }

    const int gy = oy0 + ty, gx0 = ox0 + colbase;
    const int gi = baseP + gy * Ww + gx0;
    *reinterpret_cast<float4*>(&qb[gi]) = make_float4(a0, a1, a2, a3);
    int li = (ty + 4) * S2W + colbase + 4;
    float redv = s2[li] * a0 + s2[li + 1] * a1 + s2[li + 2] * a2 + s2[li + 3] * a3;
    float tot = blockReduce(redv, red, tid);
    if (tid == 0) {
        int blk = c * (GXc * GYc) + blockIdx.y * GXc + blockIdx.x;
        part[((size_t)b * 4 + 1) * PB + blk] = tot;
    }
}

// ---------------------------------------------------------------------
// k_gradL:
// mode 0 (GRAD, always): g = corr15T(w) + reg-prior grad; r=p=-g; slot2=||r||^2.
//   tgt never read: v - tgt == sign(v)*min(|v|, thr) (exact); thr==null -> tgt==0.
//   allrp2 && thr==null && interior block -> composite C stencil.
// mode 1 (HESS fallback, only when !allrp2): original path, reads tgt for fac.
// ---------------------------------------------------------------------
__global__ __launch_bounds__(256)
void k_gradL(const float* __restrict__ kx, const float* __restrict__ wb,
             const float* __restrict__ xg,
             const float* __restrict__ rb, const float* __restrict__ pbuf,
             const float* __restrict__ tgt, const float* __restrict__ thr,
             float* __restrict__ outb,
             float* __restrict__ pout, const float* __restrict__ kernB,
             const float* __restrict__ rks, const float* __restrict__ rkw,
             const float* __restrict__ rpw, const SolveInfo* __restrict__ si,
             float* __restrict__ part, const CgState* __restrict__ st,
             const int* __restrict__ ncg, int iter, int mode)
{
    if (mode == 1 && si->allrp2) return;
    const int pz = blockIdx.z, b = pz / Cn, c = pz % Cn;
    const CgState s = st[b];
    if (mode == 1 && (s.done != 0 || iter >= *ncg)) return;
    __shared__ __align__(16) float wt[SA * THt];    // also reused as ph
    __shared__ __align__(16) float s2[S2W * S2H];
    __shared__ __align__(16) float sC[81];
    __shared__ float rk5[NRK * 25];
    __shared__ float srkw[NRK], srpw[NRK], sthr[NRK];
    __shared__ float red[256];
    float* ph = wt;
    const int tx = threadIdx.x, ty = threadIdx.y, tid = ty * 16 + tx;
    const int ox0 = blockIdx.x * BX, oy0 = blockIdx.y * BY;
    const int baseP = pz * PLANE;
    const float beta = s.beta; const int pf = s.pflag;
    const float* wsrc = si->fastBank ? kx : wb;
    const float* kp = kernB + b * 225;

    for (int i = tid; i < 81; i += 256) sC[i] = si->C[i];
    for (int i = tid; i < NRK * 25; i += 256) rk5[i] = rks[i];
    if (tid < NRK) {
        srkw[tid] = rkw[tid]; srpw[tid] = rpw[tid];
        sthr[tid] = thr ? thr[tid] : 0.f;
    }

    for (int i = tid; i < 78 * THt; i += 256) {
        int ly = i / 78, lx = i % 78;
        int gy = oy0 - KR + ly, gx = ox0 - KR + lx;
        wt[ly * SA + lx] = (gy >= 0 && gy < Hh && gx >= 0 && gx < Ww)
                           ? wsrc[baseP + gy * Ww + gx] : 0.f;
    }
    for (int i = tid; i < S2W * S2H; i += 256) {
        int ly = i / S2W, lx = i % S2W;
        int gy = oy0 - 4 + ly, gx = ox0 - 4 + lx;
        float v = 0.f;
        if (gy >= 0 && gy < Hh && gx >= 0 && gx < Ww) {
            int gi = baseP + gy * Ww + gx;
            if (mode == 0) v = xg[gi];
            else { float rv = rb[gi], pv = pbuf[gi]; v = pf ? fmaf(beta, pv, rv) : pv; }
        }
        s2[i] = v;
    }
    __syncthreads();

    const int colbase = tx * 4;
    float a0 = 0.f, a1 = 0.f, a2 = 0.f, a3 = 0.f;
    for (int i = 0; i < KS; i++) {
        const float4* rp4 = reinterpret_cast<const float4*>(&wt[(ty + i) * SA + colbase]);
        float f[20];
        #pragma unroll
        for (int s5 = 0; s5 < 5; s5++) {
            float4 w4 = rp4[s5];
            f[s5 * 4] = w4.x; f[s5 * 4 + 1] = w4.y; f[s5 * 4 + 2] = w4.z; f[s5 * 4 + 3] = w4.w;
        }
        const float* kr = kp + (14 - i) * 15;
        #pragma unroll
        for (int j = 0; j < KS; j++) {
            float kv = kr[14 - j];
            a0 = fmaf(kv, f[j], a0); a1 = fmaf(kv, f[j + 1], a1);
            a2 = fmaf(kv, f[j + 2], a2); a3 = fmaf(kv, f[j + 3], a3);
        }
    }

    const bool blkInterior = (oy0 >= 2) && (oy0 + BY - 1 <= Hh - 3) &&
                             (ox0 >= 2) && (ox0 + BX - 1 <= Ww - 3);
    if (mode == 0 && si->allrp2 && thr == nullptr && blkInterior) {
        // solve-1 interior: reg grad = C * x (eps term ~1e-10)
        #pragma unroll
        for (int oy = 0; oy < 9; oy++) {
            float cr[9]; bool nz = false;
            #pragma unroll
            for (int ox = 0; ox < 9; ox++) { cr[ox] = sC[oy * 9 + ox]; nz = nz || (cr[ox] != 0.f); }
            if (!nz) continue;
            const float4* s4 = reinterpret_cast<const float4*>(&s2[(ty + oy) * S2W + colbase]);
            float4 u0 = s4[0], u1 = s4[1], u2 = s4[2];
            float f12[12] = {u0.x,u0.y,u0.z,u0.w,u1.x,u1.y,u1.z,u1.w,u2.x,u2.y,u2.z,u2.w};
            #pragma unroll
            for (int ox = 0; ox < 9; ox++) {
                float kv = cr[ox];
                if (kv != 0.f) {
                    a0 = fmaf(kv, f12[ox], a0); a1 = fmaf(kv, f12[ox + 1], a1);
                    a2 = fmaf(kv, f12[ox + 2], a2); a3 = fmaf(kv, f12[ox + 3], a3);
                }
            }
        }
    } else {
        __syncthreads();   // wt fully consumed; ph (alias) may now be written
        for (int m = 0; m < NRK; m++) {
            float wm = srkw[m], rp = srpw[m];
            if (wm == 0.f) continue;
            float rmr[25];
            #pragma unroll
            for (int q = 0; q < 25; q++) rmr[q] = rk5[m * 25 + q];
            const float* tgm = (mode == 1 && tgt)
                ? tgt + ((size_t)(b * NRK + m)) * CHW + (size_t)c * PLANE : nullptr;
            const float coefG = wm * rp;
            const float coefH = wm * rp * (rp - 1.f);
            const float thrm = sthr[m];

            for (int t = tid; t < PHG; t += 256) {
                int zy = t / 17, zx0 = (t % 17) * 4;
                int gy = oy0 - 2 + zy, gx0 = ox0 - 2 + zx0;
                float v0 = 0.f, v1 = 0.f, v2 = 0.f, v3 = 0.f;
                #pragma unroll
                for (int a = 0; a < 5; a++) {
                    bool rz = rmr[a*5]==0.f && rmr[a*5+1]==0.f && rmr[a*5+2]==0.f &&
                              rmr[a*5+3]==0.f && rmr[a*5+4]==0.f;
                    if (rz) continue;
                    const float4* s4 = reinterpret_cast<const float4*>(&s2[(zy + a) * S2W + zx0]);
                    float4 u0 = s4[0], u1 = s4[1];
                    float f8[8] = {u0.x,u0.y,u0.z,u0.w,u1.x,u1.y,u1.z,u1.w};
                    #pragma unroll
                    for (int bb = 0; bb < 5; bb++) {
                        float kv = rmr[a * 5 + bb];
                        if (kv != 0.f) {
                            v0 = fmaf(kv, f8[bb], v0); v1 = fmaf(kv, f8[bb+1], v1);
                            v2 = fmaf(kv, f8[bb+2], v2); v3 = fmaf(kv, f8[bb+3], v3);
                        }
                    }
                }
                bool gyin = (gy >= 0 && gy < Hh);
                float o0 = 0.f, o1 = 0.f, o2 = 0.f, o3 = 0.f;
                #pragma unroll
                for (int j = 0; j < 4; j++) {
                    int gx = gx0 + j;
                    if (!gyin || gx < 0 || gx >= Ww) continue;
                    float v = (j == 0) ? v0 : (j == 1) ? v1 : (j == 2) ? v2 : v3;
                    float o;
                    if (mode == 0) {
                        if (thr) {   // v - shrink(v,thr) == sign(v)*min(|v|,thr)
                            float sgv = (v > 0.f) ? 1.f : ((v < 0.f) ? -1.f : 0.f);
                            v = sgv * fminf(fabsf(v), thrm);
                        }
                        float sg = (v > 0.f) ? 1.f : ((v < 0.f) ? -1.f : 0.f);
                        float av = fabsf(v) + EPSf;
                        o = coefG * sg * ((rp == 2.f) ? av : powf(av, rp - 1.f));
                    } else {
                        float fac = 1.f;
                        if (rp != 2.f) {
                            float vx = 0.f;
                            for (int a = 0; a < 5; a++)
                                for (int bb = 0; bb < 5; bb++) {
                                    int yy = gy - 2 + a, xx = gx - 2 + bb;
                                    if (yy >= 0 && yy < Hh && xx >= 0 && xx < Ww)
                                        vx = fmaf(rmr[a * 5 + bb], xg[baseP + yy * Ww + xx], vx);
                                }
                            if (tgm) vx -= tgm[gy * Ww + gx];
                            fac = powf(fabsf(vx) + EPSf, rp - 2.f);
                        }
                        o = coefH * fac * v;
                    }
                    if (j == 0) o0 = o; else if (j == 1) o1 = o; else if (j == 2) o2 = o; else o3 = o;
                }
                *reinterpret_cast<float4*>(&ph[zy * PHW + zx0]) = make_float4(o0, o1, o2, o3);
            }
            __syncthreads();
            #pragma unroll
            for (int a = 0; a < 5; a++) {
                int fr = 4 - a;
                bool rz = rmr[fr*5]==0.f && rmr[fr*5+1]==0.f && rmr[fr*5+2]==0.f &&
                          rmr[fr*5+3]==0.f && rmr[fr*5+4]==0.f;
                if (rz) continue;
                const float4* q4 = reinterpret_cast<const float4*>(&ph[(ty + a) * PHW + colbase]);
                float4 u0 = q4[0], u1 = q4[1];
                float f8[8] = {u0.x,u0.y,u0.z,u0.w,u1.x,u1.y,u1.z,u1.w};
                #pragma unroll
                for (int bb = 0; bb < 5; bb++) {
                    float kv = rmr[fr * 5 + (4 - bb)];
                    if (kv != 0.f) {
                        a0 = fmaf(kv, f8[bb], a0); a1 = fmaf(kv, f8[bb+1], a1);
                        a2 = fmaf(kv, f8[bb+2], a2); a3 = fmaf(kv, f8[bb+3], a3);
                    }
                }
            }
            __syncthreads();
        }
    }

    const int gi = baseP + (oy0 + ty) * Ww + ox0 + colbase;
    float redv;
    if (mode == 0) {
        float r0v = -a0, r1v = -a1, r2v = -a2, r3v = -a3;
        float4 rv4 = make_float4(r0v, r1v, r2v, r3v);
        *reinterpret_cast<float4*>(&outb[gi]) = rv4;
        *reinterpret_cast<float4*>(&pout[gi]) = rv4;
        redv = r0v * r0v + r1v * r1v + r2v * r2v + r3v * r3v;
    } else {
        *reinterpret_cast<float4*>(&outb[gi]) = make_float4(a0, a1, a2, a3);
        int li = (ty + 4) * S2W + colbase + 4;
        redv = s2[li] * a0 + s2[li + 1] * a1 + s2[li + 2] * a2 + s2[li + 3] * a3;
    }
    float tot = blockReduce(redv, red, tid);
    if (tid == 0) {
        int blk = c * (GXc * GYc) + blockIdx.y * GXc + blockIdx.x;
        int slot = (mode == 0) ? 2 : 1;
        part[((size_t)b * 4 + slot) * PB + blk] = tot;
    }
}

// ---------------------------------------------------------------------
// k_axpy: recompute alpha in-block from slot0/slot1 (no atomics, no fences);
// x += alpha*pn ; r -= alpha*q ; slot2 = ||r_new||^2.
// ---------------------------------------------------------------------
__global__ __launch_bounds__(256)
void k_axpy(float4* __restrict__ x, float4* __restrict__ r,
            const float4* __restrict__ pn, const float4* __restrict__ q,
            float* __restrict__ part, const CgState* __restrict__ st,
            const int* __restrict__ ncg, int iter)
{
    const int b = blockIdx.y;
    const CgState s = st[b];
    if (s.done != 0 || iter >= *ncg) return;
    __shared__ float red[256];
    const int tid = threadIdx.x;
    // alpha = num/den recomputed per block (partials visible via stream order)
    float sn = 0.f, sd = 0.f;
    for (int i = tid; i < PB; i += 256) {
        sn += part[((size_t)b * 4 + 0) * PB + i];
        sd += part[((size_t)b * 4 + 1) * PB + i];
    }
    float num = blockReduce(sn, red, tid);
    float den = blockReduce(sd, red, tid);
    const float alpha = num / (den + 1e-12f);
    const int idx = b * (CHW / 4) + blockIdx.x * 256 + tid;
    float4 pc = pn[idx], rv = r[idx], qv = q[idx], xv = x[idx];
    xv.x = fmaf(alpha, pc.x, xv.x); xv.y = fmaf(alpha, pc.y, xv.y);
    xv.z = fmaf(alpha, pc.z, xv.z); xv.w = fmaf(alpha, pc.w, xv.w);
    rv.x = fmaf(-alpha, qv.x, rv.x); rv.y = fmaf(-alpha, qv.y, rv.y);
    rv.z = fmaf(-alpha, qv.z, rv.z); rv.w = fmaf(-alpha, qv.w, rv.w);
    x[idx] = xv; r[idx] = rv;
    float nr = rv.x * rv.x + rv.y * rv.y + rv.z * rv.z + rv.w * rv.w;
    float tot = blockReduce(nr, red, tid);
    if (tid == 0) part[((size_t)b * 4 + 2) * PB + blockIdx.x] = tot;
}

// k_fin_iter: mode 0 = CG state init; mode 1 = beta/done update (2 blocks).
__global__ __launch_bounds__(256)
void k_fin_iter(const float* __restrict__ part, CgState* st,
                const int* __restrict__ ncg, int iter, int mode)
{
    const int b = blockIdx.x, tid = threadIdx.x;
    __shared__ float red[256];
    if (mode == 1 && (st[b].done != 0 || iter >= *ncg)) { if (tid == 0) st[b].pflag = 0; return; }
    float s = 0.f;
    for (int i = tid; i < PB; i += 256) s += part[((size_t)b * 4 + 2) * PB + i];
    float nrn = blockReduce(s, red, tid);
    if (tid == 0) {
        if (mode == 0) {
            st[b].rn = nrn; st[b].r0 = nrn; st[b].done = 0; st[b].pflag = 0;
            st[b].beta = 0.f; st[b].alpha = 0.f;
        } else {
            float beta = nrn / (st[b].rn + 1e-20f);
            int conv = (nrn < CGTOL * st[b].r0) ? 1 : 0;
            st[b].beta = beta; st[b].rn = nrn;
            st[b].pflag = conv ? 0 : 1;
            if (conv) st[b].done = 1;
        }
    }
}

// ------------------------- bilateral grid -------------------------
__global__ __launch_bounds__(64)
void k_splat(const float* __restrict__ x, float* __restrict__ grid)
{
    __shared__ float bins[NBn * 2];
    const int tid = threadIdx.y * 8 + threadIdx.x;
    if (tid < NBn * 2) bins[tid] = 0.f;
    __syncthreads();
    const int pz = blockIdx.z;
    const int gy = blockIdx.y, gx = blockIdx.x;
    const int py = gy * 8 + threadIdx.y, px = gx * 8 + threadIdx.x;
    float I = x[(size_t)pz * PLANE + py * Ww + px];
    float Ic = fminf(fmaxf(I, 0.f), 1.f);
    int zi = (int)rintf(Ic * (NBn - 1));
    zi = min(max(zi, 0), NBn - 1);
    atomicAdd(&bins[zi * 2], Ic);
    atomicAdd(&bins[zi * 2 + 1], 1.f);
    __syncthreads();
    if (tid < NBn * 2)
        grid[(size_t)pz * GH * GW * NBn * 2 + ((size_t)gy * GW + gx) * NBn * 2 + tid] = bins[tid];
}

__global__ __launch_bounds__(256)
void k_blur(const float* __restrict__ in, float* __restrict__ out,
            const float* __restrict__ taps, int ntaps, int axis)
{
    const int id = blockIdx.x * 256 + threadIdx.x;
    const int total = Bn * Cn * GH * GW * NBn;
    if (id >= total) return;
    const int z = id % NBn;
    const int x = (id / NBn) % GW;
    const int y = (id / (NBn * GW)) % GH;
    const int p = id / (NBn * GW * GH);
    int coord, lim; long stride;
    if (axis == 0)      { coord = y; lim = GH;  stride = (long)GW * NBn * 2; }
    else if (axis == 1) { coord = x; lim = GW;  stride = NBn * 2; }
    else                { coord = z; lim = NBn; stride = 2; }
    const long base = (((long)(p * GH + y) * GW + x) * NBn + z) * 2;
    const int r = ntaps / 2;
    float a0 = 0.f, a1 = 0.f;
    for (int t = 0; t < ntaps; t++) {
        int cc = coord + t - r;
        if (cc < 0 || cc >= lim) continue;
        float w = taps[t];
        long ofs = base + (long)(cc - coord) * stride;
        a0 = fmaf(w, in[ofs], a0);
        a1 = fmaf(w, in[ofs + 1], a1);
    }
    out[base] = a0; out[base + 1] = a1;
}

__global__ __launch_bounds__(256)
void k_slice(const float* __restrict__ xin, const float* __restrict__ grid,
             float* __restrict__ xout)
{
    const int pz = blockIdx.z;
    const int id = blockIdx.x * 256 + threadIdx.x;
    const int py = id / Ww, px = id % Ww;
    float I = xin[(size_t)pz * PLANE + id];
    float Ic = fminf(fmaxf(I, 0.f), 1.f);
    float yf = (float)py / SS, xf = (float)px / SS, zf = Ic * (NBn - 1);
    int y0 = min(max((int)floorf(yf), 0), GH - 1); int y1 = min(y0 + 1, GH - 1);
    float wy = fminf(fmaxf(yf - (float)y0, 0.f), 1.f);
    int x0 = min(max((int)floorf(xf), 0), GW - 1); int x1 = min(x0 + 1, GW - 1);
    float wx = fminf(fmaxf(xf - (float)x0, 0.f), 1.f);
    int z0 = min(max((int)floorf(zf), 0), NBn - 1); int z1 = min(z0 + 1, NBn - 1);
    float wz = fminf(fmaxf(zf - (float)z0, 0.f), 1.f);
    const float* gp = grid + (size_t)pz * GH * GW * NBn * 2;
    const int   ys[2] = { y0, y1 };  const float wys[2] = { 1.f - wy, wy };
    const int   xs[2] = { x0, x1 };  const float wxs[2] = { 1.f - wx, wx };
    const int   zs[2] = { z0, z1 };  const float wzs[2] = { 1.f - wz, wz };
    float a0 = 0.f, a1 = 0.f;
    for (int iy = 0; iy < 2; iy++)
        for (int ix = 0; ix < 2; ix++)
            for (int iz = 0; iz < 2; iz++) {
                float w = wys[iy] * wxs[ix] * wzs[iz];
                size_t idx = (((size_t)ys[iy] * GW + xs[ix]) * NBn + zs[iz]) * 2;
                a0 = fmaf(w, gp[idx], a0);
                a1 = fmaf(w, gp[idx + 1], a1);
            }
    xout[(size_t)pz * PLANE + id] = a0 / (a1 + 1e-8f);
}

// k_prior: builds reg targets; only needed for the !allrp2 fallback Hessian.
__global__ __launch_bounds__(256)
void k_prior(const float* __restrict__ x, float* __restrict__ tgt,
             const float* __restrict__ rks, const float* __restrict__ thr,
             const SolveInfo* __restrict__ si)
{
    if (si->allrp2) return;   // tgt unread on the hot path (clip identity)
    const int pz = blockIdx.z, b = pz / Cn, c = pz % Cn;
    __shared__ float xl[24 * 24];
    __shared__ float rkk[NRK * 25];
    __shared__ float sthr[NRK];
    const int tx = threadIdx.x, ty = threadIdx.y, tid = ty * 16 + tx;
    const int ox0 = blockIdx.x * 16, oy0 = blockIdx.y * 16;
    const int baseP = pz * PLANE;
    for (int i = tid; i < NRK * 25; i += 256) rkk[i] = rks[i];
    if (tid < NRK) sthr[tid] = thr[tid];
    for (int i = tid; i < 24 * 24; i += 256) {
        int ly = i / 24, lx = i % 24;
        int gy = oy0 - 2 + ly, gx = ox0 - 2 + lx;
        xl[i] = (gy >= 0 && gy < Hh && gx >= 0 && gx < Ww) ? x[baseP + gy * Ww + gx] : 0.f;
    }
    __syncthreads();
    const int pix = (oy0 + ty) * Ww + (ox0 + tx);
    for (int m = 0; m < NRK; m++) {
        const float* rm = &rkk[m * 25];
        float v = 0.f;
        #pragma unroll
        for (int a = 0; a < 5; a++)
            #pragma unroll
            for (int bb = 0; bb < 5; bb++)
                v = fmaf(rm[a * 5 + bb], xl[(ty + a) * 24 + (tx + bb)], v);
        float sg = (v > 0.f) ? 1.f : ((v < 0.f) ? -1.f : 0.f);
        tgt[((size_t)(b * NRK + m)) * CHW + (size_t)c * PLANE + pix] =
            sg * fmaxf(fabsf(v) - sthr[m], 0.f);
    }
}

// ------------------------------ host ------------------------------
extern "C" void kernel_launch(void* const* d_in, const int* in_sizes, int n_in,
                              void* d_out, int out_size, void* d_ws, size_t ws_size,
                              hipStream_t stream)
{
    const float* blurred = (const float*)d_in[0];
    const float* kern    = (const float*)d_in[1];
    const float* dks     = (const float*)d_in[2];
    const float* dkw     = (const float*)d_in[3];
    const float* rks     = (const float*)d_in[4];
    const float* rkw     = (const float*)d_in[5];
    const float* rpw     = (const float*)d_in[6];
    const float* fs      = (const float*)d_in[7];
    const float* fr      = (const float*)d_in[8];
    const float* thr     = (const float*)d_in[9];
    const int*   ncg     = (const int*)d_in[10];
    (void)in_sizes; (void)n_in; (void)out_size; (void)ws_size;

    float* w = (float*)d_ws;
    size_t off = 0;
    auto alloc = [&](size_t n) { float* p = w + off; off += n; return p; };
    float* xb    = alloc((size_t)Bn * CHW);
    float* pbufA = alloc((size_t)Bn * CHW);
    float* pbufB = alloc((size_t)Bn * CHW);
    float* rbuf  = alloc((size_t)Bn * CHW);
    float* kx    = alloc((size_t)Bn * CHW);
    float* wb    = alloc((size_t)Bn * CHW);
    float* qb    = alloc((size_t)Bn * CHW);
    float* tg    = alloc((size_t)Bn * NRK * CHW);
    float* g0    = alloc((size_t)Bn * Cn * GH * GW * NBn * 2);
    float* g1    = alloc((size_t)Bn * Cn * GH * GW * NBn * 2);
    float* part  = alloc((size_t)Bn * 4 * PB);
    CgState* st = (CgState*)(w + off); off += Bn * 8;
    SolveInfo* sinf = (SolveInfo*)(w + off); off += 2 * ((sizeof(SolveInfo) + 3) / 4);

    dim3 tb(16, 16), grd(GXc, GYc, Bn * Cn);

    k_comp<<<2, 128, 0, stream>>>(dkw, dks, rkw, rpw, rks, sinf);

    auto solve = [&](int idx, const float* tgt_i, const float* thr_i, int initmode) {
        const float* dks_i = dks + (size_t)idx * NDK * 25;
        const float* dkw_i = dkw + (size_t)idx * NDK;
        const float* rks_i = rks + (size_t)idx * NRK * 25;
        const float* rkw_i = rkw + (size_t)idx * NRK;
        const float* rpw_i = rpw + (size_t)idx * NRK;
        const SolveInfo* si = sinf + idx;
        // init: Kx-b (bank-scaled if fast) -> [generic bank] -> gradient
        k_conv15<<<grd, tb, 0, stream>>>(initmode == 0 ? blurred : xb, nullptr, nullptr,
                                         initmode == 0 ? xb : nullptr, blurred, kx, kern,
                                         nullptr, si, st, ncg, 0, initmode == 0 ? 0 : 3);
        k_bank<<<grd, tb, 0, stream>>>(kx, wb, dks_i, dkw_i, si, st, ncg, 0, 0);
        k_gradL<<<grd, tb, 0, stream>>>(kx, wb, xb, nullptr, nullptr, tgt_i, thr_i,
                                        rbuf, pbufA, kern,
                                        rks_i, rkw_i, rpw_i, si, part, st, ncg, 0, 0);
        k_fin_iter<<<Bn, 256, 0, stream>>>(part, st, ncg, 0, 0);
        float* pcur = pbufA;   // p direction from previous iteration
        float* pnxt = pbufB;   // p_cur written by conv15 this iteration
        for (int i = 0; i < NITER; i++) {
            k_conv15<<<grd, tb, 0, stream>>>(nullptr, rbuf, pcur, pnxt, nullptr, kx, kern,
                                             part, si, st, ncg, i, 2);
            k_bank<<<grd, tb, 0, stream>>>(kx, wb, dks_i, dkw_i, si, st, ncg, i, 1);
            k_hess<<<grd, tb, 0, stream>>>(kx, wb, pnxt, qb, kern,
                                           rks_i, rkw_i, rpw_i, si, part, st, ncg, i);
            k_gradL<<<grd, tb, 0, stream>>>(kx, wb, xb, rbuf, pnxt, tgt_i, thr_i, qb, nullptr,
                                            kern, rks_i, rkw_i, rpw_i, si, part, st, ncg, i, 1);
            k_axpy<<<dim3(PB, Bn), 256, 0, stream>>>((float4*)xb, (float4*)rbuf,
                                                     (const float4*)pnxt, (const float4*)qb,
                                                     part, st, ncg, i);
            k_fin_iter<<<Bn, 256, 0, stream>>>(part, st, ncg, i, 1);
            float* tswap = pcur; pcur = pnxt; pnxt = tswap;
        }
    };

    // CG solve 1 (idx 0, zero reg targets, x0 = blurred)
    solve(0, nullptr, nullptr, 0);

    // bilateral grid stage (stage 0), in-place on xb
    dim3 sb(8, 8), sg(GW, GH, Bn * Cn);
    k_splat<<<sg, sb, 0, stream>>>(xb, g0);
    const int totalg = Bn * Cn * GH * GW * NBn;
    k_blur<<<(totalg + 255) / 256, 256, 0, stream>>>(g0, g1, fs, 11, 0);
    k_blur<<<(totalg + 255) / 256, 256, 0, stream>>>(g1, g0, fs, 11, 1);
    k_blur<<<(totalg + 255) / 256, 256, 0, stream>>>(g0, g1, fr, 5, 2);
    k_slice<<<dim3(PLANE / 256, 1, Bn * Cn), 256, 0, stream>>>(xb, g1, xb);

    // shrinkage prior -> reg targets (only materialized for !allrp2 fallback)
    k_prior<<<dim3(Ww / 16, Hh / 16, Bn * Cn), tb, 0, stream>>>(xb, tg, rks + NRK * 25, thr,
                                                                sinf + 1);

    // CG solve 2 (idx 1, targets via clip identity, x0 = bilateral output)
    solve(1, tg, thr, 1);

    hipMemcpyAsync(d_out, xb, (size_t)Bn * CHW * sizeof(float),
                   hipMemcpyDeviceToDevice, stream);
}